// Round 2
// baseline (2843.690 us; speedup 1.0000x reference)
//
#include <hip/hip_runtime.h>

typedef unsigned short u16;
typedef __attribute__((ext_vector_type(8))) short short8;
typedef __attribute__((ext_vector_type(4))) float f32x4;
typedef __attribute__((ext_vector_type(4))) unsigned short u16x4;

#define TT 100
#define NB 256
#define NN 2048
#define KREC 4096

// ws layout (bytes); total ~151.2 MB
#define OFF_FFH   0ull            // bf16 [100][256][2048]  104857600
#define OFF_FFEX  104857600ull    // fp32 [2][256][2048]      4194304
#define OFF_BC    109051904ull    // bf16 [2048][4096]       16777216
#define OFF_WH    125829120ull    // bf16 [2048][512]         2097152
#define OFF_WL    127926272ull    // bf16 [2048][512]         2097152
#define OFF_XH01  130023424ull    // bf16 [512][512]           524288
#define OFF_XL01  130547712ull    // bf16 [512][512]           524288
#define OFF_COLS  131072000ull    // fp32 [2048]                 8192
#define OFF_PARTC 131080192ull    // fp32 [16][2048]           131072
#define OFF_SPK   131211264ull    // bf16 [256][2048]         1048576
#define OFF_MEMB  132259840ull    // fp32 [256][2048]         2097152
#define OFF_PART  134356992ull    // fp32 [8][256][2048]     16777216
#define OFF_SYNC  151134208ull    // int  cnt, gen, flags[102]

__device__ __forceinline__ u16 f2bf(float f){
    unsigned int x = __float_as_uint(f);
    x += 0x7fffu + ((x >> 16) & 1u);          // RNE to bf16
    return (u16)(x >> 16);
}
__device__ __forceinline__ float bf2f(u16 u){
    return __uint_as_float(((unsigned int)u) << 16);
}

// ---------------- prep kernels ----------------

// W_fc [2048][512] fp32 -> Wh/Wl bf16
__global__ void prep_w(const float* __restrict__ Wfc, u16* __restrict__ Wh, u16* __restrict__ Wl){
    int idx = blockIdx.x * 256 + threadIdx.x;      // 1,048,576
    float v = Wfc[idx];
    u16 h = f2bf(v);
    Wh[idx] = h;
    Wl[idx] = f2bf(v - bf2f(h));
}

// x slices t=0,1 -> xh01/xl01 [(t*256+b)][512]
__global__ void prep_x01(const float* __restrict__ x, u16* __restrict__ xh, u16* __restrict__ xl){
    int idx = blockIdx.x * 256 + threadIdx.x;      // 262,144 = 2*256*512
    int t = idx >> 17;
    int r = idx & 131071;
    int b = r >> 9;
    int i = r & 511;
    float v = x[((size_t)b * TT + t) * 512 + i];
    u16 h = f2bf(v);
    size_t o = ((size_t)t * NB + b) * 512 + i;
    xh[o] = h;
    xl[o] = f2bf(v - bf2f(h));
}

// eff_rec[i][n] -> Bc[n][i]=hi, Bc[n][2048+i]=lo (transpose via LDS)
__global__ void prep_rec(const float* __restrict__ rec, const float* __restrict__ msk,
                         const float* __restrict__ bin, u16* __restrict__ Bc){
    __shared__ u16 hs[64][66];
    __shared__ u16 ls[64][66];
    int tid = threadIdx.x;
    int tm = tid & 63, t4 = tid >> 6;
    int m0 = blockIdx.x * 64, n0 = blockIdx.y * 64;
    #pragma unroll
    for (int j = 0; j < 16; ++j){
        int nl = t4 + j * 4;
        size_t gi = (size_t)(n0 + nl) * NN + m0 + tm;
        float e = rec[gi] * msk[gi] * bin[gi];
        u16 h = f2bf(e);
        hs[nl][tm] = h;
        ls[nl][tm] = f2bf(e - bf2f(h));
    }
    __syncthreads();
    #pragma unroll
    for (int j = 0; j < 16; ++j){
        int ml = t4 + j * 4;
        size_t o = (size_t)(m0 + ml) * KREC + n0 + tm;
        Bc[o]        = hs[tm][ml];
        Bc[o + 2048] = ls[tm][ml];
    }
}

// colsum[j] = sum_i eff_rec[i][j], two-stage deterministic fp32
__global__ void colsum1(const float* __restrict__ rec, const float* __restrict__ msk,
                        const float* __restrict__ bin, float* __restrict__ partc){
    int j = blockIdx.x * 256 + threadIdx.x;   // 2048
    int c = blockIdx.y;                       // 16 chunks of 128 rows
    float acc = 0.f;
    for (int ii = 0; ii < 128; ++ii){
        size_t gi = (size_t)(c * 128 + ii) * NN + j;
        acc += rec[gi] * msk[gi] * bin[gi];
    }
    partc[(size_t)c * NN + j] = acc;
}
__global__ void colsum2(const float* __restrict__ partc, float* __restrict__ cs){
    int j = blockIdx.x * 256 + threadIdx.x;
    float s = 0.f;
    #pragma unroll
    for (int c = 0; c < 16; ++c) s += partc[(size_t)c * NN + j];
    cs[j] = s;
}

// ---------------- ff GEMMs ----------------
// ffh[t*256+b][n] = bf16( sum_k bf16(x[b][t][k]) * Wh[n][k] ), K=512
__global__ __launch_bounds__(512, 2) void ff_hi_gemm(const float* __restrict__ x,
    const u16* __restrict__ Wh, u16* __restrict__ ffh)
{
    __shared__ u16 Ab[2][8192];
    __shared__ u16 Bb[2][8192];
    const int tid = threadIdx.x, lane = tid & 63, w = tid >> 6;
    const int l7 = lane & 7, l8 = lane >> 3;
    const int bn = blockIdx.x;       // 16
    const int mt = blockIdx.y;       // 200
    const int wm = w >> 2, wn = w & 3;

    auto load_tile = [&](int kt, short8* pa, short8* pb){
        int k0 = kt * 64;
        #pragma unroll
        for (int j = 0; j < 2; ++j){
            int chunk = w * 2 + j;
            int row = chunk * 8 + l8;
            int m = mt * 128 + row;
            int tt2 = m >> 8, b = m & 255;
            const float* gx = x + ((size_t)(b * TT + tt2) * 512) + k0 + (l7 << 3);
            f32x4 f0 = *reinterpret_cast<const f32x4*>(gx);
            f32x4 f1 = *reinterpret_cast<const f32x4*>(gx + 4);
            short8 v;
            #pragma unroll
            for (int i = 0; i < 4; ++i){
                v[i]     = (short)f2bf(f0[i]);
                v[i + 4] = (short)f2bf(f1[i]);
            }
            pa[j] = v;
            pb[j] = *reinterpret_cast<const short8*>(Wh + (size_t)(bn * 128 + row) * 512 + k0 + (l7 << 3));
        }
    };
    auto write_tile = [&](int sel, const short8* pa, const short8* pb){
        #pragma unroll
        for (int j = 0; j < 2; ++j){
            int chunk = w * 2 + j;
            int idx = chunk * 512 + l8 * 64 + ((l7 ^ l8) << 3);
            *reinterpret_cast<short8*>(&Ab[sel][idx]) = pa[j];
            *reinterpret_cast<short8*>(&Bb[sel][idx]) = pb[j];
        }
    };

    f32x4 zero = {0.f, 0.f, 0.f, 0.f};
    f32x4 acc[4][2];
    #pragma unroll
    for (int mi = 0; mi < 4; ++mi)
        #pragma unroll
        for (int ni = 0; ni < 2; ++ni) acc[mi][ni] = zero;

    short8 ra[2], rb[2], na[2], nb[2];
    load_tile(0, ra, rb);
    write_tile(0, ra, rb);
    __syncthreads();

    for (int kt = 0; kt < 8; ++kt){
        int sel = kt & 1;
        if (kt + 1 < 8) load_tile(kt + 1, na, nb);
        #pragma unroll
        for (int kk2 = 0; kk2 < 2; ++kk2){
            int ke = kk2 * 32 + ((lane >> 4) << 3);
            short8 af[4], bfr[2];
            #pragma unroll
            for (int mi = 0; mi < 4; ++mi){
                int row = wm * 64 + mi * 16 + (lane & 15);
                int byte = (row * 128 + ke * 2) ^ ((row & 7) << 4);
                af[mi] = *reinterpret_cast<const short8*>(reinterpret_cast<const char*>(Ab[sel]) + byte);
            }
            #pragma unroll
            for (int ni = 0; ni < 2; ++ni){
                int row = wn * 32 + ni * 16 + (lane & 15);
                int byte = (row * 128 + ke * 2) ^ ((row & 7) << 4);
                bfr[ni] = *reinterpret_cast<const short8*>(reinterpret_cast<const char*>(Bb[sel]) + byte);
            }
            #pragma unroll
            for (int mi = 0; mi < 4; ++mi)
                #pragma unroll
                for (int ni = 0; ni < 2; ++ni)
                    acc[mi][ni] = __builtin_amdgcn_mfma_f32_16x16x32_bf16(af[mi], bfr[ni], acc[mi][ni], 0, 0, 0);
        }
        if (kt + 1 < 8) write_tile((kt + 1) & 1, na, nb);
        __syncthreads();
    }

    const int r4 = (lane >> 4) << 2;
    const int c  = lane & 15;
    #pragma unroll
    for (int mi = 0; mi < 4; ++mi)
        #pragma unroll
        for (int ni = 0; ni < 2; ++ni){
            int n = bn * 128 + wn * 32 + ni * 16 + c;
            #pragma unroll
            for (int jj = 0; jj < 4; ++jj){
                int m = mt * 128 + wm * 64 + mi * 16 + r4 + jj;
                ffh[(size_t)m * NN + n] = f2bf(acc[mi][ni][jj]);
            }
        }
}

// exact ff for t=0,1: [xh|xh|xl] . [Wh|Wl|Wh]^T, K=1536, fp32 out
__global__ __launch_bounds__(512, 2) void ff_ex_gemm(const u16* __restrict__ xh01,
    const u16* __restrict__ xl01, const u16* __restrict__ Wh, const u16* __restrict__ Wl,
    float* __restrict__ ffex)
{
    __shared__ u16 Ab[2][8192];
    __shared__ u16 Bb[2][8192];
    const int tid = threadIdx.x, lane = tid & 63, w = tid >> 6;
    const int l7 = lane & 7, l8 = lane >> 3;
    const int bn = blockIdx.x;       // 16
    const int mt = blockIdx.y;       // 4
    const int wm = w >> 2, wn = w & 3;

    auto load_tile = [&](int kt, short8* pa, short8* pb){
        int k0 = kt * 64;
        int reg = k0 >> 9;
        int kk = k0 & 511;
        const u16* ab = (reg == 2) ? xl01 : xh01;
        const u16* bb = (reg == 1) ? Wl : Wh;
        #pragma unroll
        for (int j = 0; j < 2; ++j){
            int chunk = w * 2 + j;
            int row = chunk * 8 + l8;
            pa[j] = *reinterpret_cast<const short8*>(ab + (size_t)(mt * 128 + row) * 512 + kk + (l7 << 3));
            pb[j] = *reinterpret_cast<const short8*>(bb + (size_t)(bn * 128 + row) * 512 + kk + (l7 << 3));
        }
    };
    auto write_tile = [&](int sel, const short8* pa, const short8* pb){
        #pragma unroll
        for (int j = 0; j < 2; ++j){
            int chunk = w * 2 + j;
            int idx = chunk * 512 + l8 * 64 + ((l7 ^ l8) << 3);
            *reinterpret_cast<short8*>(&Ab[sel][idx]) = pa[j];
            *reinterpret_cast<short8*>(&Bb[sel][idx]) = pb[j];
        }
    };

    f32x4 zero = {0.f, 0.f, 0.f, 0.f};
    f32x4 acc[4][2];
    #pragma unroll
    for (int mi = 0; mi < 4; ++mi)
        #pragma unroll
        for (int ni = 0; ni < 2; ++ni) acc[mi][ni] = zero;

    short8 ra[2], rb[2], na[2], nb[2];
    load_tile(0, ra, rb);
    write_tile(0, ra, rb);
    __syncthreads();

    for (int kt = 0; kt < 24; ++kt){
        int sel = kt & 1;
        if (kt + 1 < 24) load_tile(kt + 1, na, nb);
        #pragma unroll
        for (int kk2 = 0; kk2 < 2; ++kk2){
            int ke = kk2 * 32 + ((lane >> 4) << 3);
            short8 af[4], bfr[2];
            #pragma unroll
            for (int mi = 0; mi < 4; ++mi){
                int row = wm * 64 + mi * 16 + (lane & 15);
                int byte = (row * 128 + ke * 2) ^ ((row & 7) << 4);
                af[mi] = *reinterpret_cast<const short8*>(reinterpret_cast<const char*>(Ab[sel]) + byte);
            }
            #pragma unroll
            for (int ni = 0; ni < 2; ++ni){
                int row = wn * 32 + ni * 16 + (lane & 15);
                int byte = (row * 128 + ke * 2) ^ ((row & 7) << 4);
                bfr[ni] = *reinterpret_cast<const short8*>(reinterpret_cast<const char*>(Bb[sel]) + byte);
            }
            #pragma unroll
            for (int mi = 0; mi < 4; ++mi)
                #pragma unroll
                for (int ni = 0; ni < 2; ++ni)
                    acc[mi][ni] = __builtin_amdgcn_mfma_f32_16x16x32_bf16(af[mi], bfr[ni], acc[mi][ni], 0, 0, 0);
        }
        if (kt + 1 < 24) write_tile((kt + 1) & 1, na, nb);
        __syncthreads();
    }

    const int r4 = (lane >> 4) << 2;
    const int c  = lane & 15;
    #pragma unroll
    for (int mi = 0; mi < 4; ++mi)
        #pragma unroll
        for (int ni = 0; ni < 2; ++ni){
            int n = bn * 128 + wn * 32 + ni * 16 + c;
            #pragma unroll
            for (int jj = 0; jj < 4; ++jj){
                int m = mt * 128 + wm * 64 + mi * 16 + r4 + jj;
                ffex[(size_t)m * NN + n] = acc[mi][ni][jj];
            }
        }
}

// ---------------- persistent time-loop kernel ----------------
// 256 blocks x 512 threads, manual device-scope grid barrier.
// flags[t]: bit0 = all spikes at t-1 fired, bit1 = all zero; else dense GEMM.
__global__ __launch_bounds__(512, 1) void snn_persist(
    const u16* __restrict__ Bc, const u16* __restrict__ ffh,
    const float* __restrict__ ffex, const float* __restrict__ colsum,
    u16* __restrict__ spk, float* __restrict__ memb,
    float* __restrict__ part, int* __restrict__ sync, float* __restrict__ out)
{
    __shared__ u16 Ab[2][8192];
    __shared__ u16 Bb[2][8192];
    __shared__ int redA[8];
    __shared__ int redZ[8];
    const int tid = threadIdx.x, lane = tid & 63, w = tid >> 6;
    const int l7 = lane & 7, l8 = lane >> 3;
    int* cnt = sync;
    int* gen = sync + 1;
    int* flags = sync + 2;
    const int bid = blockIdx.x;

    auto gbar = [&](){
        asm volatile("s_waitcnt vmcnt(0) lgkmcnt(0)" ::: "memory");
        __syncthreads();
        if (tid == 0){
            __threadfence();   // flush this block's stores past L2 (agent scope)
            int g = __hip_atomic_load(gen, __ATOMIC_RELAXED, __HIP_MEMORY_SCOPE_AGENT);
            int a = __hip_atomic_fetch_add(cnt, 1, __ATOMIC_ACQ_REL, __HIP_MEMORY_SCOPE_AGENT);
            if (a == (int)gridDim.x - 1){
                __hip_atomic_store(cnt, 0, __ATOMIC_RELAXED, __HIP_MEMORY_SCOPE_AGENT);
                __hip_atomic_fetch_add(gen, 1, __ATOMIC_RELEASE, __HIP_MEMORY_SCOPE_AGENT);
            } else {
                while (__hip_atomic_load(gen, __ATOMIC_ACQUIRE, __HIP_MEMORY_SCOPE_AGENT) == g)
                    __builtin_amdgcn_s_sleep(2);
            }
            __threadfence();   // invalidate caches before reading others' data
        }
        __syncthreads();
    };

    if (bid == 0 && tid <= TT) flags[tid] = (tid == 0) ? 2 : 3;
    gbar();

    // dense-GEMM decomposition (per-block constants)
    const int bn = bid & 15, my = (bid >> 4) & 1, ks = bid >> 5;
    const int kstart = ks << 9, acol = kstart & 2047;
    const int wm = w >> 2, wn = w & 3;
    const int b_own = bid;

    for (int t = 0; t < TT; ++t){
        int flag = flags[t];

        if (!(flag & 3)){
            // ---------- dense GEMM: partial[ks][b][n] = sum_k spk[b][k]*Bc[n][k] ----------
            auto load_tile = [&](int kt, short8* pa, short8* pb){
                int k0 = kt * 64;
                #pragma unroll
                for (int j = 0; j < 2; ++j){
                    int chunk = w * 2 + j;
                    int row = chunk * 8 + l8;
                    const u16* ga = spk + (size_t)(my * 128 + row) * NN + acol + k0 + (l7 << 3);
                    pa[j] = *reinterpret_cast<const short8*>(ga);
                    const u16* gb = Bc + (size_t)(bn * 128 + row) * KREC + kstart + k0 + (l7 << 3);
                    pb[j] = *reinterpret_cast<const short8*>(gb);
                }
            };
            auto write_tile = [&](int sel, const short8* pa, const short8* pb){
                #pragma unroll
                for (int j = 0; j < 2; ++j){
                    int chunk = w * 2 + j;
                    int idx = chunk * 512 + l8 * 64 + ((l7 ^ l8) << 3);
                    *reinterpret_cast<short8*>(&Ab[sel][idx]) = pa[j];
                    *reinterpret_cast<short8*>(&Bb[sel][idx]) = pb[j];
                }
            };

            f32x4 zero = {0.f, 0.f, 0.f, 0.f};
            f32x4 acc[4][2];
            #pragma unroll
            for (int mi = 0; mi < 4; ++mi)
                #pragma unroll
                for (int ni = 0; ni < 2; ++ni) acc[mi][ni] = zero;

            short8 ra[2], rb[2], na[2], nb[2];
            load_tile(0, ra, rb);
            write_tile(0, ra, rb);
            __syncthreads();

            for (int kt = 0; kt < 8; ++kt){
                int sel = kt & 1;
                if (kt + 1 < 8) load_tile(kt + 1, na, nb);
                #pragma unroll
                for (int kk2 = 0; kk2 < 2; ++kk2){
                    int ke = kk2 * 32 + ((lane >> 4) << 3);
                    short8 af[4], bfr[2];
                    #pragma unroll
                    for (int mi = 0; mi < 4; ++mi){
                        int row = wm * 64 + mi * 16 + (lane & 15);
                        int byte = (row * 128 + ke * 2) ^ ((row & 7) << 4);
                        af[mi] = *reinterpret_cast<const short8*>(reinterpret_cast<const char*>(Ab[sel]) + byte);
                    }
                    #pragma unroll
                    for (int ni = 0; ni < 2; ++ni){
                        int row = wn * 32 + ni * 16 + (lane & 15);
                        int byte = (row * 128 + ke * 2) ^ ((row & 7) << 4);
                        bfr[ni] = *reinterpret_cast<const short8*>(reinterpret_cast<const char*>(Bb[sel]) + byte);
                    }
                    #pragma unroll
                    for (int mi = 0; mi < 4; ++mi)
                        #pragma unroll
                        for (int ni = 0; ni < 2; ++ni)
                            acc[mi][ni] = __builtin_amdgcn_mfma_f32_16x16x32_bf16(af[mi], bfr[ni], acc[mi][ni], 0, 0, 0);
                }
                if (kt + 1 < 8) write_tile((kt + 1) & 1, na, nb);
                __syncthreads();
            }

            float* pp = part + (size_t)ks * (NB * NN);
            const int r4 = (lane >> 4) << 2;
            const int c  = lane & 15;
            #pragma unroll
            for (int mi = 0; mi < 4; ++mi)
                #pragma unroll
                for (int ni = 0; ni < 2; ++ni){
                    int n = bn * 128 + wn * 32 + ni * 16 + c;
                    #pragma unroll
                    for (int jj = 0; jj < 4; ++jj){
                        int b = my * 128 + wm * 64 + mi * 16 + r4 + jj;
                        pp[(size_t)b * NN + n] = acc[mi][ni][jj];
                    }
                }
            gbar();
        }

        // ---------- LIF phase: block owns batch row b_own ----------
        {
            const int n0 = tid << 2;
            float ffv[4];
            if (t < 2){
                f32x4 fe = *reinterpret_cast<const f32x4*>(ffex + ((size_t)t * NB + b_own) * NN + n0);
                #pragma unroll
                for (int k = 0; k < 4; ++k) ffv[k] = fe[k];
            } else {
                u16x4 fh = *reinterpret_cast<const u16x4*>(ffh + ((size_t)t * NB + b_own) * NN + n0);
                #pragma unroll
                for (int k = 0; k < 4; ++k) ffv[k] = bf2f(fh[k]);
            }

            float mem[4];
            if (flag & 1){            // all fired: reset wipes mem; cur = colsum + ff
                f32x4 cs = *reinterpret_cast<const f32x4*>(colsum + n0);
                #pragma unroll
                for (int k = 0; k < 4; ++k) mem[k] = cs[k] + ffv[k];
            } else if (flag & 2){     // all zero: cur = ff
                f32x4 mb = *reinterpret_cast<const f32x4*>(memb + (size_t)b_own * NN + n0);
                #pragma unroll
                for (int k = 0; k < 4; ++k) mem[k] = 0.96f * mb[k] + ffv[k];
            } else {                  // mixed: combine split-K partials
                f32x4 mb = *reinterpret_cast<const f32x4*>(memb + (size_t)b_own * NN + n0);
                u16x4 sp = *reinterpret_cast<const u16x4*>(spk + (size_t)b_own * NN + n0);
                float p[4] = {0.f, 0.f, 0.f, 0.f};
                #pragma unroll
                for (int ks2 = 0; ks2 < 8; ++ks2){
                    f32x4 pv = *reinterpret_cast<const f32x4*>(part + (size_t)ks2 * (NB * NN) + (size_t)b_own * NN + n0);
                    #pragma unroll
                    for (int k = 0; k < 4; ++k) p[k] += pv[k];
                }
                #pragma unroll
                for (int k = 0; k < 4; ++k){
                    float sprev = sp[k] ? 1.f : 0.f;
                    mem[k] = 0.96f * mb[k] * (1.f - sprev) + p[k] + ffv[k];
                }
            }

            int s[4];
            u16x4 sv;
            f32x4 mv;
            #pragma unroll
            for (int k = 0; k < 4; ++k){
                s[k] = (mem[k] >= 1.0f);
                sv[k] = s[k] ? (u16)0x3F80 : (u16)0;
                mv[k] = mem[k];
            }
            *reinterpret_cast<u16x4*>(spk + (size_t)b_own * NN + n0) = sv;
            *reinterpret_cast<f32x4*>(memb + (size_t)b_own * NN + n0) = mv;
            if (n0 >= 2000 - 3){
                #pragma unroll
                for (int k = 0; k < 4; ++k){
                    int n = n0 + k;
                    if (n >= 2000)
                        out[((size_t)b_own * TT + t) * 48 + (n - 2000)] = s[k] ? 1.f : 0.f;
                }
            }

            int af = s[0] & s[1] & s[2] & s[3];
            int az = (!s[0]) & (!s[1]) & (!s[2]) & (!s[3]);
            unsigned long long ba = __ballot(af);
            unsigned long long bz = __ballot(az);
            if (lane == 0){
                redA[w] = (ba == ~0ull);
                redZ[w] = (bz == ~0ull);
            }
            __syncthreads();
            if (tid == 0){
                int aA = 1, aZ = 1;
                #pragma unroll
                for (int i = 0; i < 8; ++i){ aA &= redA[i]; aZ &= redZ[i]; }
                atomicAnd(&flags[t + 1], (aA ? 1 : 0) | (aZ ? 2 : 0));
            }
        }
        gbar();
    }
}

// ---------------- host ----------------
extern "C" void kernel_launch(void* const* d_in, const int* in_sizes, int n_in,
                              void* d_out, int out_size, void* d_ws, size_t ws_size,
                              hipStream_t stream)
{
    const float* x   = (const float*)d_in[0];
    const float* Wfc = (const float*)d_in[1];
    const float* rec = (const float*)d_in[2];
    const float* msk = (const float*)d_in[3];
    const float* bin = (const float*)d_in[4];
    float* out = (float*)d_out;
    char* ws = (char*)d_ws;

    u16* ffh    = (u16*)(ws + OFF_FFH);
    float* ffex = (float*)(ws + OFF_FFEX);
    u16* Bc     = (u16*)(ws + OFF_BC);
    u16* Wh     = (u16*)(ws + OFF_WH);
    u16* Wl     = (u16*)(ws + OFF_WL);
    u16* xh01   = (u16*)(ws + OFF_XH01);
    u16* xl01   = (u16*)(ws + OFF_XL01);
    float* cs   = (float*)(ws + OFF_COLS);
    float* partc= (float*)(ws + OFF_PARTC);
    u16* spk    = (u16*)(ws + OFF_SPK);
    float* memb = (float*)(ws + OFF_MEMB);
    float* part = (float*)(ws + OFF_PART);
    int* sync   = (int*)(ws + OFF_SYNC);

    hipMemsetAsync(sync, 0, 4096, stream);
    hipMemsetAsync(memb, 0, (size_t)NB * NN * sizeof(float), stream);

    prep_w<<<4096, 256, 0, stream>>>(Wfc, Wh, Wl);
    prep_x01<<<1024, 256, 0, stream>>>(x, xh01, xl01);
    prep_rec<<<dim3(32, 32), 256, 0, stream>>>(rec, msk, bin, Bc);
    colsum1<<<dim3(8, 16), 256, 0, stream>>>(rec, msk, bin, partc);
    colsum2<<<8, 256, 0, stream>>>(partc, cs);
    ff_hi_gemm<<<dim3(16, 200), 512, 0, stream>>>(x, Wh, ffh);
    ff_ex_gemm<<<dim3(16, 4), 512, 0, stream>>>(xh01, xl01, Wh, Wl, ffex);
    snn_persist<<<256, 512, 0, stream>>>(Bc, ffh, ffex, cs, spk, memb, part, sync, out);
}

// Round 3
// 374.521 us; speedup vs baseline: 7.5929x; 7.5929x over previous
//
#include <hip/hip_runtime.h>

typedef unsigned short u16;
typedef __attribute__((ext_vector_type(8))) short short8;
typedef __attribute__((ext_vector_type(4))) float f32x4;
typedef __attribute__((ext_vector_type(4))) unsigned short u16x4;

#define TT 100
#define NB 256
#define NN 2048
#define KREC 4096

// ws layout (bytes)
#define OFF_FFH   0ull            // bf16 [100][256][2048]  104857600
#define OFF_FFEX  104857600ull    // fp32 [2][256][2048]      4194304
#define OFF_BC    109051904ull    // bf16 [2048][4096]       16777216
#define OFF_WH    125829120ull    // bf16 [2048][512]         2097152
#define OFF_WL    127926272ull    // bf16 [2048][512]         2097152
#define OFF_XH01  130023424ull    // bf16 [512][512]           524288
#define OFF_XL01  130547712ull    // bf16 [512][512]           524288
#define OFF_COLS  131072000ull    // fp32 [2048]                 8192
#define OFF_PARTC 131080192ull    // fp32 [32][2048]           262144
#define OFF_SPK   131342336ull    // bf16 [256][2048]         1048576
#define OFF_MEMB  132390912ull    // fp32 [256][2048]         2097152
#define OFF_PART  134488064ull    // fp32 [8][256][2048]     16777216
#define OFF_SYNC  151265280ull    // int cnt, gen, vote[100]
#define OFF_AF    151266304ull    // int AF[100]

__device__ __forceinline__ u16 f2bf(float f){
    unsigned int x = __float_as_uint(f);
    x += 0x7fffu + ((x >> 16) & 1u);          // RNE to bf16
    return (u16)(x >> 16);
}
__device__ __forceinline__ float bf2f(u16 u){
    return __uint_as_float(((unsigned int)u) << 16);
}

// ---------------- prep kernels ----------------

__global__ void prep_w(const float* __restrict__ Wfc, u16* __restrict__ Wh, u16* __restrict__ Wl){
    int idx = blockIdx.x * 256 + threadIdx.x;      // 1,048,576
    float v = Wfc[idx];
    u16 h = f2bf(v);
    Wh[idx] = h;
    Wl[idx] = f2bf(v - bf2f(h));
}

__global__ void prep_x01(const float* __restrict__ x, u16* __restrict__ xh, u16* __restrict__ xl){
    int idx = blockIdx.x * 256 + threadIdx.x;      // 262,144 = 2*256*512
    int t = idx >> 17;
    int r = idx & 131071;
    int b = r >> 9;
    int i = r & 511;
    float v = x[((size_t)b * TT + t) * 512 + i];
    u16 h = f2bf(v);
    size_t o = ((size_t)t * NB + b) * 512 + i;
    xh[o] = h;
    xl[o] = f2bf(v - bf2f(h));
}

// eff_rec transpose+split into Bc, plus deterministic colsum partials
__global__ void prep_rec(const float* __restrict__ rec, const float* __restrict__ msk,
                         const float* __restrict__ bin, u16* __restrict__ Bc,
                         float* __restrict__ partc){
    __shared__ u16 hs[64][66];
    __shared__ u16 ls[64][66];
    __shared__ float redc[4][64];
    int tid = threadIdx.x;
    int tm = tid & 63, t4 = tid >> 6;
    int m0 = blockIdx.x * 64, n0 = blockIdx.y * 64;
    float accl = 0.f;
    #pragma unroll
    for (int j = 0; j < 16; ++j){
        int nl = t4 + j * 4;
        size_t gi = (size_t)(n0 + nl) * NN + m0 + tm;
        float e = rec[gi] * msk[gi] * bin[gi];
        u16 h = f2bf(e);
        hs[nl][tm] = h;
        ls[nl][tm] = f2bf(e - bf2f(h));
        accl += e;
    }
    redc[t4][tm] = accl;
    __syncthreads();
    if (t4 == 0)
        partc[(size_t)blockIdx.y * NN + m0 + tm] =
            redc[0][tm] + redc[1][tm] + redc[2][tm] + redc[3][tm];
    #pragma unroll
    for (int j = 0; j < 16; ++j){
        int ml = t4 + j * 4;
        size_t o = (size_t)(m0 + ml) * KREC + n0 + tm;
        Bc[o]        = hs[tm][ml];
        Bc[o + 2048] = ls[tm][ml];
    }
}

__global__ void colsum2(const float* __restrict__ partc, float* __restrict__ cs){
    int j = blockIdx.x * 256 + threadIdx.x;   // 2048
    float s = 0.f;
    #pragma unroll
    for (int c = 0; c < 32; ++c) s += partc[(size_t)c * NN + j];
    cs[j] = s;
}

// ---------------- ff GEMMs ----------------
// ffh = bf16(x_hi @ Wh^T) for all t, fused hypothesis epilogue:
// AF[t] &= all(colsum+ff >= 1); out[b][t][:] = (colsum+ff >= 1) for readout cols.
__global__ __launch_bounds__(512, 2) void ff_hi_gemm(const float* __restrict__ x,
    const u16* __restrict__ Wh, u16* __restrict__ ffh,
    const float* __restrict__ colsum, int* __restrict__ AF, float* __restrict__ out)
{
    __shared__ u16 Ab[2][8192];
    __shared__ u16 Bb[2][8192];
    __shared__ int redH[8];
    const int tid = threadIdx.x, lane = tid & 63, w = tid >> 6;
    const int l7 = lane & 7, l8 = lane >> 3;
    const int bn = blockIdx.x;       // 16
    const int mt = blockIdx.y;       // 200
    const int wm = w >> 2, wn = w & 3;

    auto load_tile = [&](int kt, short8* pa, short8* pb){
        int k0 = kt * 64;
        #pragma unroll
        for (int j = 0; j < 2; ++j){
            int chunk = w * 2 + j;
            int row = chunk * 8 + l8;
            int m = mt * 128 + row;
            int tt2 = m >> 8, b = m & 255;
            const float* gx = x + ((size_t)(b * TT + tt2) * 512) + k0 + (l7 << 3);
            f32x4 f0 = *reinterpret_cast<const f32x4*>(gx);
            f32x4 f1 = *reinterpret_cast<const f32x4*>(gx + 4);
            short8 v;
            #pragma unroll
            for (int i = 0; i < 4; ++i){
                v[i]     = (short)f2bf(f0[i]);
                v[i + 4] = (short)f2bf(f1[i]);
            }
            pa[j] = v;
            pb[j] = *reinterpret_cast<const short8*>(Wh + (size_t)(bn * 128 + row) * 512 + k0 + (l7 << 3));
        }
    };
    auto write_tile = [&](int sel, const short8* pa, const short8* pb){
        #pragma unroll
        for (int j = 0; j < 2; ++j){
            int chunk = w * 2 + j;
            int idx = chunk * 512 + l8 * 64 + ((l7 ^ l8) << 3);
            *reinterpret_cast<short8*>(&Ab[sel][idx]) = pa[j];
            *reinterpret_cast<short8*>(&Bb[sel][idx]) = pb[j];
        }
    };

    f32x4 zero = {0.f, 0.f, 0.f, 0.f};
    f32x4 acc[4][2];
    #pragma unroll
    for (int mi = 0; mi < 4; ++mi)
        #pragma unroll
        for (int ni = 0; ni < 2; ++ni) acc[mi][ni] = zero;

    short8 ra[2], rb[2], na[2], nb[2];
    load_tile(0, ra, rb);
    write_tile(0, ra, rb);
    __syncthreads();

    for (int kt = 0; kt < 8; ++kt){
        int sel = kt & 1;
        if (kt + 1 < 8) load_tile(kt + 1, na, nb);
        #pragma unroll
        for (int kk2 = 0; kk2 < 2; ++kk2){
            int ke = kk2 * 32 + ((lane >> 4) << 3);
            short8 af[4], bfr[2];
            #pragma unroll
            for (int mi = 0; mi < 4; ++mi){
                int row = wm * 64 + mi * 16 + (lane & 15);
                int byte = (row * 128 + ke * 2) ^ ((row & 7) << 4);
                af[mi] = *reinterpret_cast<const short8*>(reinterpret_cast<const char*>(Ab[sel]) + byte);
            }
            #pragma unroll
            for (int ni = 0; ni < 2; ++ni){
                int row = wn * 32 + ni * 16 + (lane & 15);
                int byte = (row * 128 + ke * 2) ^ ((row & 7) << 4);
                bfr[ni] = *reinterpret_cast<const short8*>(reinterpret_cast<const char*>(Bb[sel]) + byte);
            }
            #pragma unroll
            for (int mi = 0; mi < 4; ++mi)
                #pragma unroll
                for (int ni = 0; ni < 2; ++ni)
                    acc[mi][ni] = __builtin_amdgcn_mfma_f32_16x16x32_bf16(af[mi], bfr[ni], acc[mi][ni], 0, 0, 0);
        }
        if (kt + 1 < 8) write_tile((kt + 1) & 1, na, nb);
        __syncthreads();
    }

    const int r4 = (lane >> 4) << 2;
    const int c  = lane & 15;
    const int t_out = mt >> 1;
    int ok = 1;
    float cs0 = colsum[bn * 128 + wn * 32 + c];
    float cs1 = colsum[bn * 128 + wn * 32 + 16 + c];
    #pragma unroll
    for (int mi = 0; mi < 4; ++mi)
        #pragma unroll
        for (int ni = 0; ni < 2; ++ni){
            int n = bn * 128 + wn * 32 + ni * 16 + c;
            float csv = ni ? cs1 : cs0;
            #pragma unroll
            for (int jj = 0; jj < 4; ++jj){
                int m = mt * 128 + wm * 64 + mi * 16 + r4 + jj;
                float v = acc[mi][ni][jj];
                ffh[(size_t)m * NN + n] = f2bf(v);
                int sp = (v + csv >= 1.0f) ? 1 : 0;
                ok &= sp;
                if (bn == 15 && n >= 2000){
                    int b = m & 255;
                    out[((size_t)b * TT + t_out) * 48 + (n - 2000)] = sp ? 1.f : 0.f;
                }
            }
        }
    unsigned long long bb = __ballot(ok != 0);
    if (lane == 0) redH[w] = (bb == ~0ull) ? 1 : 0;
    __syncthreads();
    if (tid == 0){
        int a = 1;
        #pragma unroll
        for (int i = 0; i < 8; ++i) a &= redH[i];
        atomicAnd(&AF[t_out], a ? ~0 : 0);
    }
}

// exact ff for t=0,1: [xh|xh|xl] . [Wh|Wl|Wh]^T, K=1536, fp32 out
__global__ __launch_bounds__(512, 2) void ff_ex_gemm(const u16* __restrict__ xh01,
    const u16* __restrict__ xl01, const u16* __restrict__ Wh, const u16* __restrict__ Wl,
    float* __restrict__ ffex)
{
    __shared__ u16 Ab[2][8192];
    __shared__ u16 Bb[2][8192];
    const int tid = threadIdx.x, lane = tid & 63, w = tid >> 6;
    const int l7 = lane & 7, l8 = lane >> 3;
    const int bn = blockIdx.x;       // 16
    const int mt = blockIdx.y;       // 4
    const int wm = w >> 2, wn = w & 3;

    auto load_tile = [&](int kt, short8* pa, short8* pb){
        int k0 = kt * 64;
        int reg = k0 >> 9;
        int kk = k0 & 511;
        const u16* ab = (reg == 2) ? xl01 : xh01;
        const u16* bb2 = (reg == 1) ? Wl : Wh;
        #pragma unroll
        for (int j = 0; j < 2; ++j){
            int chunk = w * 2 + j;
            int row = chunk * 8 + l8;
            pa[j] = *reinterpret_cast<const short8*>(ab + (size_t)(mt * 128 + row) * 512 + kk + (l7 << 3));
            pb[j] = *reinterpret_cast<const short8*>(bb2 + (size_t)(bn * 128 + row) * 512 + kk + (l7 << 3));
        }
    };
    auto write_tile = [&](int sel, const short8* pa, const short8* pb){
        #pragma unroll
        for (int j = 0; j < 2; ++j){
            int chunk = w * 2 + j;
            int idx = chunk * 512 + l8 * 64 + ((l7 ^ l8) << 3);
            *reinterpret_cast<short8*>(&Ab[sel][idx]) = pa[j];
            *reinterpret_cast<short8*>(&Bb[sel][idx]) = pb[j];
        }
    };

    f32x4 zero = {0.f, 0.f, 0.f, 0.f};
    f32x4 acc[4][2];
    #pragma unroll
    for (int mi = 0; mi < 4; ++mi)
        #pragma unroll
        for (int ni = 0; ni < 2; ++ni) acc[mi][ni] = zero;

    short8 ra[2], rb[2], na[2], nb[2];
    load_tile(0, ra, rb);
    write_tile(0, ra, rb);
    __syncthreads();

    for (int kt = 0; kt < 24; ++kt){
        int sel = kt & 1;
        if (kt + 1 < 24) load_tile(kt + 1, na, nb);
        #pragma unroll
        for (int kk2 = 0; kk2 < 2; ++kk2){
            int ke = kk2 * 32 + ((lane >> 4) << 3);
            short8 af[4], bfr[2];
            #pragma unroll
            for (int mi = 0; mi < 4; ++mi){
                int row = wm * 64 + mi * 16 + (lane & 15);
                int byte = (row * 128 + ke * 2) ^ ((row & 7) << 4);
                af[mi] = *reinterpret_cast<const short8*>(reinterpret_cast<const char*>(Ab[sel]) + byte);
            }
            #pragma unroll
            for (int ni = 0; ni < 2; ++ni){
                int row = wn * 32 + ni * 16 + (lane & 15);
                int byte = (row * 128 + ke * 2) ^ ((row & 7) << 4);
                bfr[ni] = *reinterpret_cast<const short8*>(reinterpret_cast<const char*>(Bb[sel]) + byte);
            }
            #pragma unroll
            for (int mi = 0; mi < 4; ++mi)
                #pragma unroll
                for (int ni = 0; ni < 2; ++ni)
                    acc[mi][ni] = __builtin_amdgcn_mfma_f32_16x16x32_bf16(af[mi], bfr[ni], acc[mi][ni], 0, 0, 0);
        }
        if (kt + 1 < 24) write_tile((kt + 1) & 1, na, nb);
        __syncthreads();
    }

    const int r4 = (lane >> 4) << 2;
    const int c  = lane & 15;
    #pragma unroll
    for (int mi = 0; mi < 4; ++mi)
        #pragma unroll
        for (int ni = 0; ni < 2; ++ni){
            int n = bn * 128 + wn * 32 + ni * 16 + c;
            #pragma unroll
            for (int jj = 0; jj < 4; ++jj){
                int m = mt * 128 + wm * 64 + mi * 16 + r4 + jj;
                ffex[(size_t)m * NN + n] = acc[mi][ni][jj];
            }
        }
}

// ---------------- sequential persistent kernel with AF fast-forward ----------------
__global__ __launch_bounds__(512, 1) void snn_seq(
    const u16* __restrict__ Bc, const u16* __restrict__ ffh,
    const float* __restrict__ ffex, const float* __restrict__ colsum,
    const int* __restrict__ AF, u16* __restrict__ spk, float* __restrict__ memb,
    float* __restrict__ part, int* __restrict__ sync, float* __restrict__ out)
{
    __shared__ u16 Ab[2][8192];
    __shared__ u16 Bb[2][8192];
    __shared__ int red[8];
    __shared__ int bcast;
    __shared__ int firstbad;
    const int tid = threadIdx.x, lane = tid & 63, w = tid >> 6;
    const int l7 = lane & 7, l8 = lane >> 3;
    const int bid = blockIdx.x;
    int* cnt = sync;
    int* gen = sync + 1;
    int* vote = sync + 2;
    const int b_own = bid;
    const int n0 = tid << 2;
    const int bn = bid & 15, my = (bid >> 4) & 1, ks = bid >> 5;
    const int kstart = ks << 9, acol = kstart & 2047;
    const int wm = w >> 2, wn = w & 3;

    auto gbar = [&](){
        asm volatile("s_waitcnt vmcnt(0) lgkmcnt(0)" ::: "memory");
        __syncthreads();
        if (tid == 0){
            __threadfence();
            int g = __hip_atomic_load(gen, __ATOMIC_RELAXED, __HIP_MEMORY_SCOPE_AGENT);
            int a = __hip_atomic_fetch_add(cnt, 1, __ATOMIC_ACQ_REL, __HIP_MEMORY_SCOPE_AGENT);
            if (a == (int)gridDim.x - 1){
                __hip_atomic_store(cnt, 0, __ATOMIC_RELAXED, __HIP_MEMORY_SCOPE_AGENT);
                __hip_atomic_fetch_add(gen, 1, __ATOMIC_RELEASE, __HIP_MEMORY_SCOPE_AGENT);
            } else {
                while (__hip_atomic_load(gen, __ATOMIC_ACQUIRE, __HIP_MEMORY_SCOPE_AGENT) == g)
                    __builtin_amdgcn_s_sleep(2);
            }
            __threadfence();
        }
        __syncthreads();
    };

    auto wait_vote = [&](int t)->int{
        if (tid == 0){
            int v;
            while (((unsigned)(v = __hip_atomic_load(&vote[t], __ATOMIC_ACQUIRE, __HIP_MEMORY_SCOPE_AGENT)) >> 20) != 256u)
                __builtin_amdgcn_s_sleep(2);
            bcast = v;
        }
        __syncthreads();
        int v = bcast;
        __syncthreads();
        return v;
    };

    auto finish_step = [&](f32x4 m, int t){
        int s[4];
        u16x4 sv;
        #pragma unroll
        for (int k = 0; k < 4; ++k){
            s[k] = (m[k] >= 1.0f) ? 1 : 0;
            sv[k] = s[k] ? (u16)0x3F80 : (u16)0;
        }
        *reinterpret_cast<u16x4*>(spk + (size_t)b_own * NN + n0) = sv;
        *reinterpret_cast<f32x4*>(memb + (size_t)b_own * NN + n0) = m;
        if (n0 >= 2000){
            #pragma unroll
            for (int k = 0; k < 4; ++k)
                out[((size_t)b_own * TT + t) * 48 + (n0 + k - 2000)] = s[k] ? 1.f : 0.f;
        }
        int af = s[0] & s[1] & s[2] & s[3];
        int az = !(s[0] | s[1] | s[2] | s[3]);
        unsigned long long ba = __ballot(af != 0);
        unsigned long long bz = __ballot(az != 0);
        if (lane == 0) red[w] = ((ba == ~0ull) ? 1 : 0) | ((bz == ~0ull) ? 2 : 0);
        __syncthreads();
        if (tid == 0){
            int a = 3;
            #pragma unroll
            for (int i = 0; i < 8; ++i) a &= red[i];
            __hip_atomic_fetch_add(&vote[t], (1 << 20) | (a & 1) | ((a >> 1) << 10),
                                   __ATOMIC_RELEASE, __HIP_MEMORY_SCOPE_AGENT);
        }
        __syncthreads();
    };

    auto load_ff = [&](int t)->f32x4{
        f32x4 f;
        if (t < 2){
            f = *reinterpret_cast<const f32x4*>(ffex + ((size_t)t * NB + b_own) * NN + n0);
        } else {
            u16x4 fh = *reinterpret_cast<const u16x4*>(ffh + ((size_t)t * NB + b_own) * NN + n0);
            #pragma unroll
            for (int k = 0; k < 4; ++k) f[k] = bf2f(fh[k]);
        }
        return f;
    };

    // t = 0: prior state all zero -> mem = ff (exact)
    {
        f32x4 m = load_ff(0);
        finish_step(m, 0);
    }

    int t = 1;
    while (t < TT){
        int v = wait_vote(t - 1);
        int naf = v & 0x3FF;
        int naz = (v >> 10) & 0x3FF;

        if (naf == 256){
            // all spikes at t-1 fired: hyp outputs valid while AF chain holds
            if (tid == 0) firstbad = TT;
            __syncthreads();
            int idx = t + tid;
            if (idx < TT && AF[idx] == 0) atomicMin(&firstbad, idx);
            __syncthreads();
            int h = firstbad;
            if (h == TT) return;                      // all remaining outputs already correct
            // materialize state after step h (flag[h]=AF so mem = colsum + ff[h])
            f32x4 cs = *reinterpret_cast<const f32x4*>(colsum + n0);
            f32x4 ffv = load_ff(h);
            f32x4 m;
            #pragma unroll
            for (int k = 0; k < 4; ++k) m[k] = cs[k] + ffv[k];
            finish_step(m, h);
            t = h + 1;
        } else if (naz == 256){
            // all zero: cur = ff
            f32x4 ffv = load_ff(t);
            f32x4 mb = *reinterpret_cast<const f32x4*>(memb + (size_t)b_own * NN + n0);
            f32x4 m;
            #pragma unroll
            for (int k = 0; k < 4; ++k) m[k] = 0.96f * mb[k] + ffv[k];
            finish_step(m, t);
            ++t;
        } else {
            // ---------- mixed: dense split-K GEMM over spikes ----------
            gbar();   // flush own spk/memb writes, invalidate for cross-block reads
            auto load_tile = [&](int kt, short8* pa, short8* pb){
                int k0 = kt * 64;
                #pragma unroll
                for (int j = 0; j < 2; ++j){
                    int chunk = w * 2 + j;
                    int row = chunk * 8 + l8;
                    const u16* ga = spk + (size_t)(my * 128 + row) * NN + acol + k0 + (l7 << 3);
                    pa[j] = *reinterpret_cast<const short8*>(ga);
                    const u16* gb = Bc + (size_t)(bn * 128 + row) * KREC + kstart + k0 + (l7 << 3);
                    pb[j] = *reinterpret_cast<const short8*>(gb);
                }
            };
            auto write_tile = [&](int sel, const short8* pa, const short8* pb){
                #pragma unroll
                for (int j = 0; j < 2; ++j){
                    int chunk = w * 2 + j;
                    int idx = chunk * 512 + l8 * 64 + ((l7 ^ l8) << 3);
                    *reinterpret_cast<short8*>(&Ab[sel][idx]) = pa[j];
                    *reinterpret_cast<short8*>(&Bb[sel][idx]) = pb[j];
                }
            };

            f32x4 zero = {0.f, 0.f, 0.f, 0.f};
            f32x4 acc[4][2];
            #pragma unroll
            for (int mi = 0; mi < 4; ++mi)
                #pragma unroll
                for (int ni = 0; ni < 2; ++ni) acc[mi][ni] = zero;

            short8 ra[2], rb[2], na[2], nb[2];
            load_tile(0, ra, rb);
            write_tile(0, ra, rb);
            __syncthreads();

            for (int kt = 0; kt < 8; ++kt){
                int sel = kt & 1;
                if (kt + 1 < 8) load_tile(kt + 1, na, nb);
                #pragma unroll
                for (int kk2 = 0; kk2 < 2; ++kk2){
                    int ke = kk2 * 32 + ((lane >> 4) << 3);
                    short8 af2[4], bfr[2];
                    #pragma unroll
                    for (int mi = 0; mi < 4; ++mi){
                        int row = wm * 64 + mi * 16 + (lane & 15);
                        int byte = (row * 128 + ke * 2) ^ ((row & 7) << 4);
                        af2[mi] = *reinterpret_cast<const short8*>(reinterpret_cast<const char*>(Ab[sel]) + byte);
                    }
                    #pragma unroll
                    for (int ni = 0; ni < 2; ++ni){
                        int row = wn * 32 + ni * 16 + (lane & 15);
                        int byte = (row * 128 + ke * 2) ^ ((row & 7) << 4);
                        bfr[ni] = *reinterpret_cast<const short8*>(reinterpret_cast<const char*>(Bb[sel]) + byte);
                    }
                    #pragma unroll
                    for (int mi = 0; mi < 4; ++mi)
                        #pragma unroll
                        for (int ni = 0; ni < 2; ++ni)
                            acc[mi][ni] = __builtin_amdgcn_mfma_f32_16x16x32_bf16(af2[mi], bfr[ni], acc[mi][ni], 0, 0, 0);
                }
                if (kt + 1 < 8) write_tile((kt + 1) & 1, na, nb);
                __syncthreads();
            }

            float* pp = part + (size_t)ks * (NB * NN);
            const int r4 = (lane >> 4) << 2;
            const int c  = lane & 15;
            #pragma unroll
            for (int mi = 0; mi < 4; ++mi)
                #pragma unroll
                for (int ni = 0; ni < 2; ++ni){
                    int n = bn * 128 + wn * 32 + ni * 16 + c;
                    #pragma unroll
                    for (int jj = 0; jj < 4; ++jj){
                        int b = my * 128 + wm * 64 + mi * 16 + r4 + jj;
                        pp[(size_t)b * NN + n] = acc[mi][ni][jj];
                    }
                }
            gbar();   // partials visible

            f32x4 ffv = load_ff(t);
            f32x4 mb = *reinterpret_cast<const f32x4*>(memb + (size_t)b_own * NN + n0);
            u16x4 sp = *reinterpret_cast<const u16x4*>(spk + (size_t)b_own * NN + n0);
            float p[4] = {0.f, 0.f, 0.f, 0.f};
            #pragma unroll
            for (int ks2 = 0; ks2 < 8; ++ks2){
                f32x4 pv = *reinterpret_cast<const f32x4*>(part + (size_t)ks2 * (NB * NN) + (size_t)b_own * NN + n0);
                #pragma unroll
                for (int k = 0; k < 4; ++k) p[k] += pv[k];
            }
            f32x4 m;
            #pragma unroll
            for (int k = 0; k < 4; ++k){
                float sprev = sp[k] ? 1.f : 0.f;
                m[k] = 0.96f * mb[k] * (1.f - sprev) + p[k] + ffv[k];
            }
            finish_step(m, t);
            ++t;
        }
    }
}

// ---------------- host ----------------
extern "C" void kernel_launch(void* const* d_in, const int* in_sizes, int n_in,
                              void* d_out, int out_size, void* d_ws, size_t ws_size,
                              hipStream_t stream)
{
    const float* x   = (const float*)d_in[0];
    const float* Wfc = (const float*)d_in[1];
    const float* rec = (const float*)d_in[2];
    const float* msk = (const float*)d_in[3];
    const float* bin = (const float*)d_in[4];
    float* out = (float*)d_out;
    char* ws = (char*)d_ws;

    u16* ffh    = (u16*)(ws + OFF_FFH);
    float* ffex = (float*)(ws + OFF_FFEX);
    u16* Bc     = (u16*)(ws + OFF_BC);
    u16* Wh     = (u16*)(ws + OFF_WH);
    u16* Wl     = (u16*)(ws + OFF_WL);
    u16* xh01   = (u16*)(ws + OFF_XH01);
    u16* xl01   = (u16*)(ws + OFF_XL01);
    float* cs   = (float*)(ws + OFF_COLS);
    float* partc= (float*)(ws + OFF_PARTC);
    u16* spk    = (u16*)(ws + OFF_SPK);
    float* memb = (float*)(ws + OFF_MEMB);
    float* part = (float*)(ws + OFF_PART);
    int* sync   = (int*)(ws + OFF_SYNC);
    int* AF     = (int*)(ws + OFF_AF);

    hipMemsetAsync(sync, 0, 1024, stream);
    hipMemsetAsync(AF, 0xFF, 512, stream);

    prep_w<<<4096, 256, 0, stream>>>(Wfc, Wh, Wl);
    prep_x01<<<1024, 256, 0, stream>>>(x, xh01, xl01);
    prep_rec<<<dim3(32, 32), 256, 0, stream>>>(rec, msk, bin, Bc, partc);
    colsum2<<<8, 256, 0, stream>>>(partc, cs);
    ff_ex_gemm<<<dim3(16, 4), 512, 0, stream>>>(xh01, xl01, Wh, Wl, ffex);
    ff_hi_gemm<<<dim3(16, 200), 512, 0, stream>>>(x, Wh, ffh, cs, AF, out);
    snn_seq<<<256, 512, 0, stream>>>(Bc, ffh, ffex, cs, AF, spk, memb, part, sync, out);
}

// Round 4
// 203.716 us; speedup vs baseline: 13.9591x; 1.8384x over previous
//
#include <hip/hip_runtime.h>

typedef unsigned short u16;
typedef __attribute__((ext_vector_type(8))) short short8;
typedef __attribute__((ext_vector_type(4))) float f32x4;
typedef __attribute__((ext_vector_type(4))) unsigned short u16x4;

#define TT 100
#define NB 256
#define NN 2048
#define KREC 4096
#define NPRE 3
#define EPS 0.25f

// ws layout (bytes); total ~51.7 MB
#define OFF_WH    0ull            // bf16 [2048][512]   2097152
#define OFF_WL    2097152ull      // bf16 [2048][512]   2097152
#define OFF_XH4   4194304ull      // bf16 [4][256][512] 1048576
#define OFF_XL4   5242880ull      // bf16 [4][256][512] 1048576
#define OFF_BC    6291456ull      // bf16 [2048][4096] 16777216
#define OFF_COLS  23068672ull     // fp32 [2048]           8192
#define OFF_PARTC 23076864ull     // fp32 [32][2048]     262144
#define OFF_FFPRE 23339008ull     // fp32 [4][256][2048] 8388608
#define OFF_SPK   31727616ull     // bf16 [256][2048]   1048576
#define OFF_MEMB  32776192ull     // fp32 [256][2048]   2097152
#define OFF_PART  34873344ull     // fp32 [8][256][2048] 16777216
#define OFF_FLAGS 51650560ull     // int flags[16]
#define OFF_AF    51650624ull     // int AF[100+pad]
#define OFF_SYNC  51651136ull     // int cnt, gen, vote[100]

__device__ __forceinline__ u16 f2bf(float f){
    unsigned int x = __float_as_uint(f);
    x += 0x7fffu + ((x >> 16) & 1u);          // RNE to bf16
    return (u16)(x >> 16);
}
__device__ __forceinline__ float bf2f(u16 u){
    return __uint_as_float(((unsigned int)u) << 16);
}

// ---------------- prep kernels ----------------

__global__ void prep_w(const float* __restrict__ Wfc, u16* __restrict__ Wh, u16* __restrict__ Wl){
    int idx = blockIdx.x * 256 + threadIdx.x;      // 1,048,576
    float v = Wfc[idx];
    u16 h = f2bf(v);
    Wh[idx] = h;
    Wl[idx] = f2bf(v - bf2f(h));
}

// x slices t=0..3 -> xh4/xl4 [(t*256+b)][512]
__global__ void prep_x4(const float* __restrict__ x, u16* __restrict__ xh, u16* __restrict__ xl){
    int idx = blockIdx.x * 256 + threadIdx.x;      // 524,288 = 4*256*512
    int t = idx >> 17;
    int r = idx & 131071;
    int b = r >> 9;
    int i = r & 511;
    float v = x[((size_t)b * TT + t) * 512 + i];
    u16 h = f2bf(v);
    size_t o = ((size_t)t * NB + b) * 512 + i;
    xh[o] = h;
    xl[o] = f2bf(v - bf2f(h));
}

// eff_rec transpose+split into Bc, plus deterministic colsum partials
__global__ void prep_rec(const float* __restrict__ rec, const float* __restrict__ msk,
                         const float* __restrict__ bin, u16* __restrict__ Bc,
                         float* __restrict__ partc){
    __shared__ u16 hs[64][66];
    __shared__ u16 ls[64][66];
    __shared__ float redc[4][64];
    int tid = threadIdx.x;
    int tm = tid & 63, t4 = tid >> 6;
    int m0 = blockIdx.x * 64, n0 = blockIdx.y * 64;
    float accl = 0.f;
    #pragma unroll
    for (int j = 0; j < 16; ++j){
        int nl = t4 + j * 4;
        size_t gi = (size_t)(n0 + nl) * NN + m0 + tm;
        float e = rec[gi] * msk[gi] * bin[gi];
        u16 h = f2bf(e);
        hs[nl][tm] = h;
        ls[nl][tm] = f2bf(e - bf2f(h));
        accl += e;
    }
    redc[t4][tm] = accl;
    __syncthreads();
    if (t4 == 0)
        partc[(size_t)blockIdx.y * NN + m0 + tm] =
            redc[0][tm] + redc[1][tm] + redc[2][tm] + redc[3][tm];
    #pragma unroll
    for (int j = 0; j < 16; ++j){
        int ml = t4 + j * 4;
        size_t o = (size_t)(m0 + ml) * KREC + n0 + tm;
        Bc[o]        = hs[tm][ml];
        Bc[o + 2048] = ls[tm][ml];
    }
}

__global__ void colsum2(const float* __restrict__ partc, float* __restrict__ cs){
    int j = blockIdx.x * 256 + threadIdx.x;   // 2048
    float s = 0.f;
    #pragma unroll
    for (int c = 0; c < 32; ++c) s += partc[(size_t)c * NN + j];
    cs[j] = s;
}

// ---------------- exact ff for t=0..NPRE: [xh|xh|xl].[Wh|Wl|Wh]^T, K=1536 ----------------
__global__ __launch_bounds__(512, 2) void ffpre_gemm(const u16* __restrict__ xh4,
    const u16* __restrict__ xl4, const u16* __restrict__ Wh, const u16* __restrict__ Wl,
    float* __restrict__ ffpre)
{
    __shared__ u16 Ab[2][8192];
    __shared__ u16 Bb[2][8192];
    const int tid = threadIdx.x, lane = tid & 63, w = tid >> 6;
    const int l7 = lane & 7, l8 = lane >> 3;
    const int bn = blockIdx.x;       // 16
    const int mt = blockIdx.y;       // 8  (M = 4*256)
    const int wm = w >> 2, wn = w & 3;

    auto load_tile = [&](int kt, short8* pa, short8* pb){
        int k0 = kt * 64;
        int reg = k0 >> 9;
        int kk = k0 & 511;
        const u16* ab = (reg == 2) ? xl4 : xh4;
        const u16* bb2 = (reg == 1) ? Wl : Wh;
        #pragma unroll
        for (int j = 0; j < 2; ++j){
            int chunk = w * 2 + j;
            int row = chunk * 8 + l8;
            pa[j] = *reinterpret_cast<const short8*>(ab + (size_t)(mt * 128 + row) * 512 + kk + (l7 << 3));
            pb[j] = *reinterpret_cast<const short8*>(bb2 + (size_t)(bn * 128 + row) * 512 + kk + (l7 << 3));
        }
    };
    auto write_tile = [&](int sel, const short8* pa, const short8* pb){
        #pragma unroll
        for (int j = 0; j < 2; ++j){
            int chunk = w * 2 + j;
            int idx = chunk * 512 + l8 * 64 + ((l7 ^ l8) << 3);
            *reinterpret_cast<short8*>(&Ab[sel][idx]) = pa[j];
            *reinterpret_cast<short8*>(&Bb[sel][idx]) = pb[j];
        }
    };

    f32x4 zero = {0.f, 0.f, 0.f, 0.f};
    f32x4 acc[4][2];
    #pragma unroll
    for (int mi = 0; mi < 4; ++mi)
        #pragma unroll
        for (int ni = 0; ni < 2; ++ni) acc[mi][ni] = zero;

    short8 ra[2], rb[2], na[2], nb[2];
    load_tile(0, ra, rb);
    write_tile(0, ra, rb);
    __syncthreads();

    for (int kt = 0; kt < 24; ++kt){
        int sel = kt & 1;
        if (kt + 1 < 24) load_tile(kt + 1, na, nb);
        #pragma unroll
        for (int kk2 = 0; kk2 < 2; ++kk2){
            int ke = kk2 * 32 + ((lane >> 4) << 3);
            short8 af[4], bfr[2];
            #pragma unroll
            for (int mi = 0; mi < 4; ++mi){
                int row = wm * 64 + mi * 16 + (lane & 15);
                int byte = (row * 128 + ke * 2) ^ ((row & 7) << 4);
                af[mi] = *reinterpret_cast<const short8*>(reinterpret_cast<const char*>(Ab[sel]) + byte);
            }
            #pragma unroll
            for (int ni = 0; ni < 2; ++ni){
                int row = wn * 32 + ni * 16 + (lane & 15);
                int byte = (row * 128 + ke * 2) ^ ((row & 7) << 4);
                bfr[ni] = *reinterpret_cast<const short8*>(reinterpret_cast<const char*>(Bb[sel]) + byte);
            }
            #pragma unroll
            for (int mi = 0; mi < 4; ++mi)
                #pragma unroll
                for (int ni = 0; ni < 2; ++ni)
                    acc[mi][ni] = __builtin_amdgcn_mfma_f32_16x16x32_bf16(af[mi], bfr[ni], acc[mi][ni], 0, 0, 0);
        }
        if (kt + 1 < 24) write_tile((kt + 1) & 1, na, nb);
        __syncthreads();
    }

    const int r4 = (lane >> 4) << 2;
    const int c  = lane & 15;
    #pragma unroll
    for (int mi = 0; mi < 4; ++mi)
        #pragma unroll
        for (int ni = 0; ni < 2; ++ni){
            int n = bn * 128 + wn * 32 + ni * 16 + c;
            #pragma unroll
            for (int jj = 0; jj < 4; ++jj){
                int m = mt * 128 + wm * 64 + mi * 16 + r4 + jj;
                ffpre[(size_t)m * NN + n] = acc[mi][ni][jj];
            }
        }
}

// ---------------- hypothesis GEMM: validate AF[t] + write hypothesis readouts ----------------
// No ffh store. AF[t]=1 only if all(colsum+ff >= 1+EPS) (margin guard).
__global__ __launch_bounds__(512, 2) void ff_hi_gemm(const float* __restrict__ x,
    const u16* __restrict__ Wh, const float* __restrict__ colsum,
    int* __restrict__ AF, float* __restrict__ out)
{
    __shared__ u16 Ab[2][8192];
    __shared__ u16 Bb[2][8192];
    __shared__ int redH[8];
    const int tid = threadIdx.x, lane = tid & 63, w = tid >> 6;
    const int l7 = lane & 7, l8 = lane >> 3;
    const int bn = blockIdx.x;       // 16
    const int mt = blockIdx.y;       // 200
    const int wm = w >> 2, wn = w & 3;

    auto load_tile = [&](int kt, short8* pa, short8* pb){
        int k0 = kt * 64;
        #pragma unroll
        for (int j = 0; j < 2; ++j){
            int chunk = w * 2 + j;
            int row = chunk * 8 + l8;
            int m = mt * 128 + row;
            int tt2 = m >> 8, b = m & 255;
            const float* gx = x + ((size_t)(b * TT + tt2) * 512) + k0 + (l7 << 3);
            f32x4 f0 = *reinterpret_cast<const f32x4*>(gx);
            f32x4 f1 = *reinterpret_cast<const f32x4*>(gx + 4);
            short8 v;
            #pragma unroll
            for (int i = 0; i < 4; ++i){
                v[i]     = (short)f2bf(f0[i]);
                v[i + 4] = (short)f2bf(f1[i]);
            }
            pa[j] = v;
            pb[j] = *reinterpret_cast<const short8*>(Wh + (size_t)(bn * 128 + row) * 512 + k0 + (l7 << 3));
        }
    };
    auto write_tile = [&](int sel, const short8* pa, const short8* pb){
        #pragma unroll
        for (int j = 0; j < 2; ++j){
            int chunk = w * 2 + j;
            int idx = chunk * 512 + l8 * 64 + ((l7 ^ l8) << 3);
            *reinterpret_cast<short8*>(&Ab[sel][idx]) = pa[j];
            *reinterpret_cast<short8*>(&Bb[sel][idx]) = pb[j];
        }
    };

    f32x4 zero = {0.f, 0.f, 0.f, 0.f};
    f32x4 acc[4][2];
    #pragma unroll
    for (int mi = 0; mi < 4; ++mi)
        #pragma unroll
        for (int ni = 0; ni < 2; ++ni) acc[mi][ni] = zero;

    short8 ra[2], rb[2], na[2], nb[2];
    load_tile(0, ra, rb);
    write_tile(0, ra, rb);
    __syncthreads();

    for (int kt = 0; kt < 8; ++kt){
        int sel = kt & 1;
        if (kt + 1 < 8) load_tile(kt + 1, na, nb);
        #pragma unroll
        for (int kk2 = 0; kk2 < 2; ++kk2){
            int ke = kk2 * 32 + ((lane >> 4) << 3);
            short8 af[4], bfr[2];
            #pragma unroll
            for (int mi = 0; mi < 4; ++mi){
                int row = wm * 64 + mi * 16 + (lane & 15);
                int byte = (row * 128 + ke * 2) ^ ((row & 7) << 4);
                af[mi] = *reinterpret_cast<const short8*>(reinterpret_cast<const char*>(Ab[sel]) + byte);
            }
            #pragma unroll
            for (int ni = 0; ni < 2; ++ni){
                int row = wn * 32 + ni * 16 + (lane & 15);
                int byte = (row * 128 + ke * 2) ^ ((row & 7) << 4);
                bfr[ni] = *reinterpret_cast<const short8*>(reinterpret_cast<const char*>(Bb[sel]) + byte);
            }
            #pragma unroll
            for (int mi = 0; mi < 4; ++mi)
                #pragma unroll
                for (int ni = 0; ni < 2; ++ni)
                    acc[mi][ni] = __builtin_amdgcn_mfma_f32_16x16x32_bf16(af[mi], bfr[ni], acc[mi][ni], 0, 0, 0);
        }
        if (kt + 1 < 8) write_tile((kt + 1) & 1, na, nb);
        __syncthreads();
    }

    const int r4 = (lane >> 4) << 2;
    const int c  = lane & 15;
    const int t_out = mt >> 1;
    int ok = 1;
    float cs0 = colsum[bn * 128 + wn * 32 + c];
    float cs1 = colsum[bn * 128 + wn * 32 + 16 + c];
    #pragma unroll
    for (int mi = 0; mi < 4; ++mi)
        #pragma unroll
        for (int ni = 0; ni < 2; ++ni){
            int n = bn * 128 + wn * 32 + ni * 16 + c;
            float csv = ni ? cs1 : cs0;
            #pragma unroll
            for (int jj = 0; jj < 4; ++jj){
                int m = mt * 128 + wm * 64 + mi * 16 + r4 + jj;
                float v = acc[mi][ni][jj] + csv;
                ok &= (v >= 1.0f + EPS) ? 1 : 0;      // fire with margin
                if (bn == 15 && n >= 2000){
                    int b = m & 255;
                    out[((size_t)b * TT + t_out) * 48 + (n - 2000)] = (v >= 1.0f) ? 1.f : 0.f;
                }
            }
        }
    unsigned long long bb = __ballot(ok != 0);
    if (lane == 0) redH[w] = (bb == ~0ull) ? 1 : 0;
    __syncthreads();
    if (tid == 0){
        int a = 1;
        #pragma unroll
        for (int i = 0; i < 8; ++i) a &= redH[i];
        atomicAnd(&AF[t_out], a ? ~0 : 0);
    }
}

// ---------------- prefix LIF kernels (stream-ordered; kernel boundary = sync) ----------------
// verdict bits: 1 = all fired, 2 = all zero, 0 = mixed

__device__ __forceinline__ void lif_finish(int b, int n0, const float mem[4], int t,
    u16* __restrict__ spk, float* __restrict__ memb, float* __restrict__ out,
    int* __restrict__ flags, int* red, int tid, int lane, int w)
{
    int s[4];
    u16x4 sv; f32x4 mv;
    #pragma unroll
    for (int k = 0; k < 4; ++k){
        s[k] = (mem[k] >= 1.0f) ? 1 : 0;
        sv[k] = s[k] ? (u16)0x3F80 : (u16)0;
        mv[k] = mem[k];
    }
    *reinterpret_cast<u16x4*>(spk + (size_t)b * NN + n0) = sv;
    *reinterpret_cast<f32x4*>(memb + (size_t)b * NN + n0) = mv;
    if (n0 >= 2000){
        #pragma unroll
        for (int k = 0; k < 4; ++k)
            out[((size_t)b * TT + t) * 48 + (n0 + k - 2000)] = s[k] ? 1.f : 0.f;
    }
    int af = s[0] & s[1] & s[2] & s[3];
    int az = !(s[0] | s[1] | s[2] | s[3]);
    unsigned long long ba = __ballot(af != 0);
    unsigned long long bz = __ballot(az != 0);
    if (lane == 0) red[w] = ((ba == ~0ull) ? 1 : 0) | ((bz == ~0ull) ? 2 : 0);
    __syncthreads();
    if (tid == 0){
        int a = 3;
        #pragma unroll
        for (int i = 0; i < 8; ++i) a &= red[i];
        atomicAnd(&flags[t], 0xFFFFFFFC | a);
    }
}

// t=0: mem = ff (exact), spikes/mem all-zero init guaranteed
__global__ __launch_bounds__(512) void lif0(const float* __restrict__ ffpre,
    u16* __restrict__ spk, float* __restrict__ memb, float* __restrict__ out,
    int* __restrict__ flags)
{
    __shared__ int red[8];
    const int tid = threadIdx.x, lane = tid & 63, w = tid >> 6;
    const int b = blockIdx.x, n0 = tid << 2;
    f32x4 fe = *reinterpret_cast<const f32x4*>(ffpre + (size_t)b * NN + n0);
    float m[4];
    #pragma unroll
    for (int k = 0; k < 4; ++k) m[k] = fe[k];
    lif_finish(b, n0, m, 0, spk, memb, out, flags, red, tid, lane, w);
}

// dense split-K GEMM over spikes; skipped unless flag[t-1] == mixed
__global__ __launch_bounds__(512, 2) void gemm_pre(
    const u16* __restrict__ Bc, const u16* __restrict__ spk,
    const int* __restrict__ flags, float* __restrict__ part, int t)
{
    if (flags[t - 1] & 3) return;
    __shared__ u16 Ab[2][8192];
    __shared__ u16 Bb[2][8192];
    const int tid = threadIdx.x, lane = tid & 63, w = tid >> 6;
    const int l7 = lane & 7, l8 = lane >> 3;
    const int bid = blockIdx.x;
    const int bn = bid & 15, my = (bid >> 4) & 1, ks = bid >> 5;
    const int kstart = ks << 9, acol = kstart & 2047;
    const int wm = w >> 2, wn = w & 3;

    auto load_tile = [&](int kt, short8* pa, short8* pb){
        int k0 = kt * 64;
        #pragma unroll
        for (int j = 0; j < 2; ++j){
            int chunk = w * 2 + j;
            int row = chunk * 8 + l8;
            const u16* ga = spk + (size_t)(my * 128 + row) * NN + acol + k0 + (l7 << 3);
            pa[j] = *reinterpret_cast<const short8*>(ga);
            const u16* gb = Bc + (size_t)(bn * 128 + row) * KREC + kstart + k0 + (l7 << 3);
            pb[j] = *reinterpret_cast<const short8*>(gb);
        }
    };
    auto write_tile = [&](int sel, const short8* pa, const short8* pb){
        #pragma unroll
        for (int j = 0; j < 2; ++j){
            int chunk = w * 2 + j;
            int idx = chunk * 512 + l8 * 64 + ((l7 ^ l8) << 3);
            *reinterpret_cast<short8*>(&Ab[sel][idx]) = pa[j];
            *reinterpret_cast<short8*>(&Bb[sel][idx]) = pb[j];
        }
    };

    f32x4 zero = {0.f, 0.f, 0.f, 0.f};
    f32x4 acc[4][2];
    #pragma unroll
    for (int mi = 0; mi < 4; ++mi)
        #pragma unroll
        for (int ni = 0; ni < 2; ++ni) acc[mi][ni] = zero;

    short8 ra[2], rb[2], na[2], nb[2];
    load_tile(0, ra, rb);
    write_tile(0, ra, rb);
    __syncthreads();

    for (int kt = 0; kt < 8; ++kt){
        int sel = kt & 1;
        if (kt + 1 < 8) load_tile(kt + 1, na, nb);
        #pragma unroll
        for (int kk2 = 0; kk2 < 2; ++kk2){
            int ke = kk2 * 32 + ((lane >> 4) << 3);
            short8 af2[4], bfr[2];
            #pragma unroll
            for (int mi = 0; mi < 4; ++mi){
                int row = wm * 64 + mi * 16 + (lane & 15);
                int byte = (row * 128 + ke * 2) ^ ((row & 7) << 4);
                af2[mi] = *reinterpret_cast<const short8*>(reinterpret_cast<const char*>(Ab[sel]) + byte);
            }
            #pragma unroll
            for (int ni = 0; ni < 2; ++ni){
                int row = wn * 32 + ni * 16 + (lane & 15);
                int byte = (row * 128 + ke * 2) ^ ((row & 7) << 4);
                bfr[ni] = *reinterpret_cast<const short8*>(reinterpret_cast<const char*>(Bb[sel]) + byte);
            }
            #pragma unroll
            for (int mi = 0; mi < 4; ++mi)
                #pragma unroll
                for (int ni = 0; ni < 2; ++ni)
                    acc[mi][ni] = __builtin_amdgcn_mfma_f32_16x16x32_bf16(af2[mi], bfr[ni], acc[mi][ni], 0, 0, 0);
        }
        if (kt + 1 < 8) write_tile((kt + 1) & 1, na, nb);
        __syncthreads();
    }

    float* pp = part + (size_t)ks * (NB * NN);
    const int r4 = (lane >> 4) << 2;
    const int c  = lane & 15;
    #pragma unroll
    for (int mi = 0; mi < 4; ++mi)
        #pragma unroll
        for (int ni = 0; ni < 2; ++ni){
            int n = bn * 128 + wn * 32 + ni * 16 + c;
            #pragma unroll
            for (int jj = 0; jj < 4; ++jj){
                int b = my * 128 + wm * 64 + mi * 16 + r4 + jj;
                pp[(size_t)b * NN + n] = acc[mi][ni][jj];
            }
        }
}

// LIF for step t in [1, NPRE]
__global__ __launch_bounds__(512) void lif_pre(const float* __restrict__ ffpre,
    const float* __restrict__ colsum, const float* __restrict__ part,
    const int* __restrict__ AF, u16* __restrict__ spk, float* __restrict__ memb,
    float* __restrict__ out, int* __restrict__ flags, int t)
{
    __shared__ int red[8];
    const int tid = threadIdx.x, lane = tid & 63, w = tid >> 6;
    const int b = blockIdx.x, n0 = tid << 2;
    int fl = flags[t - 1] & 3;
    float m[4];

    if (fl & 1){
        if (AF[t] != 0){                      // chain holds: hypothesis out[t] valid
            if (b == 0 && tid == 0) flags[t] = 1;
            return;
        }
        // AF break: materialize exactly (all fired at t-1 -> mem = colsum + ff)
        f32x4 cs = *reinterpret_cast<const f32x4*>(colsum + n0);
        f32x4 fe = *reinterpret_cast<const f32x4*>(ffpre + ((size_t)t * NB + b) * NN + n0);
        #pragma unroll
        for (int k = 0; k < 4; ++k) m[k] = cs[k] + fe[k];
    } else if (fl & 2){
        f32x4 mb = *reinterpret_cast<const f32x4*>(memb + (size_t)b * NN + n0);
        f32x4 fe = *reinterpret_cast<const f32x4*>(ffpre + ((size_t)t * NB + b) * NN + n0);
        #pragma unroll
        for (int k = 0; k < 4; ++k) m[k] = 0.96f * mb[k] + fe[k];
    } else {
        f32x4 mb = *reinterpret_cast<const f32x4*>(memb + (size_t)b * NN + n0);
        u16x4 sp = *reinterpret_cast<const u16x4*>(spk + (size_t)b * NN + n0);
        f32x4 fe = *reinterpret_cast<const f32x4*>(ffpre + ((size_t)t * NB + b) * NN + n0);
        float p[4] = {0.f, 0.f, 0.f, 0.f};
        #pragma unroll
        for (int ks2 = 0; ks2 < 8; ++ks2){
            f32x4 pv = *reinterpret_cast<const f32x4*>(part + (size_t)ks2 * (NB * NN) + (size_t)b * NN + n0);
            #pragma unroll
            for (int k = 0; k < 4; ++k) p[k] += pv[k];
        }
        #pragma unroll
        for (int k = 0; k < 4; ++k){
            float sprev = sp[k] ? 1.f : 0.f;
            m[k] = 0.96f * mb[k] * (1.f - sprev) + p[k] + fe[k];
        }
    }
    lif_finish(b, n0, m, t, spk, memb, out, flags, red, tid, lane, w);
}

// ---------------- persistent tail: t in [NPRE+1, TT) ----------------
__global__ __launch_bounds__(512, 1) void snn_tail(
    const u16* __restrict__ Bc, const float* __restrict__ x, const float* __restrict__ Wfc,
    const float* __restrict__ colsum, const int* __restrict__ AF, const int* __restrict__ flags,
    u16* __restrict__ spk, float* __restrict__ memb, float* __restrict__ part,
    int* __restrict__ sync, float* __restrict__ out)
{
    __shared__ u16 Ab[2][8192];
    __shared__ u16 Bb[2][8192];
    __shared__ float xrow[512];
    __shared__ int red[8];
    __shared__ int bcast;
    __shared__ int firstbad;
    const int tid = threadIdx.x, lane = tid & 63, w = tid >> 6;
    const int l7 = lane & 7, l8 = lane >> 3;
    const int bid = blockIdx.x;
    int* cnt = sync;
    int* gen = sync + 1;
    int* vote = sync + 2;
    const int b_own = bid;
    const int n0 = tid << 2;
    const int bn = bid & 15, my = (bid >> 4) & 1, ks = bid >> 5;
    const int kstart = ks << 9, acol = kstart & 2047;
    const int wm = w >> 2, wn = w & 3;

    auto gbar = [&](){
        asm volatile("s_waitcnt vmcnt(0) lgkmcnt(0)" ::: "memory");
        __syncthreads();
        if (tid == 0){
            __threadfence();
            int g = __hip_atomic_load(gen, __ATOMIC_RELAXED, __HIP_MEMORY_SCOPE_AGENT);
            int a = __hip_atomic_fetch_add(cnt, 1, __ATOMIC_ACQ_REL, __HIP_MEMORY_SCOPE_AGENT);
            if (a == (int)gridDim.x - 1){
                __hip_atomic_store(cnt, 0, __ATOMIC_RELAXED, __HIP_MEMORY_SCOPE_AGENT);
                __hip_atomic_fetch_add(gen, 1, __ATOMIC_RELEASE, __HIP_MEMORY_SCOPE_AGENT);
            } else {
                while (__hip_atomic_load(gen, __ATOMIC_ACQUIRE, __HIP_MEMORY_SCOPE_AGENT) == g)
                    __builtin_amdgcn_s_sleep(2);
            }
            __threadfence();
        }
        __syncthreads();
    };

    auto wait_vote = [&](int t)->int{
        if (tid == 0){
            int v;
            while (((unsigned)(v = __hip_atomic_load(&vote[t], __ATOMIC_ACQUIRE, __HIP_MEMORY_SCOPE_AGENT)) >> 20) != 256u)
                __builtin_amdgcn_s_sleep(2);
            bcast = v;
        }
        __syncthreads();
        int v = bcast;
        __syncthreads();
        int naf = ((v & 0x3FF) == 256) ? 1 : 0;
        int naz = (((v >> 10) & 0x3FF) == 256) ? 2 : 0;
        return naf | naz;
    };

    auto finish_step = [&](f32x4 m, int t){
        int s[4];
        u16x4 sv;
        #pragma unroll
        for (int k = 0; k < 4; ++k){
            s[k] = (m[k] >= 1.0f) ? 1 : 0;
            sv[k] = s[k] ? (u16)0x3F80 : (u16)0;
        }
        *reinterpret_cast<u16x4*>(spk + (size_t)b_own * NN + n0) = sv;
        *reinterpret_cast<f32x4*>(memb + (size_t)b_own * NN + n0) = m;
        if (n0 >= 2000){
            #pragma unroll
            for (int k = 0; k < 4; ++k)
                out[((size_t)b_own * TT + t) * 48 + (n0 + k - 2000)] = s[k] ? 1.f : 0.f;
        }
        int af = s[0] & s[1] & s[2] & s[3];
        int az = !(s[0] | s[1] | s[2] | s[3]);
        unsigned long long ba = __ballot(af != 0);
        unsigned long long bz = __ballot(az != 0);
        if (lane == 0) red[w] = ((ba == ~0ull) ? 1 : 0) | ((bz == ~0ull) ? 2 : 0);
        __syncthreads();
        if (tid == 0){
            int a = 3;
            #pragma unroll
            for (int i = 0; i < 8; ++i) a &= red[i];
            __hip_atomic_fetch_add(&vote[t], (1 << 20) | (a & 1) | ((a >> 1) << 10),
                                   __ATOMIC_RELEASE, __HIP_MEMORY_SCOPE_AGENT);
        }
        __syncthreads();
    };

    // exact fp32 on-the-fly ff for this block's batch row (cold path only)
    auto load_ff = [&](int tq)->f32x4{
        __syncthreads();
        xrow[tid & 511] = x[((size_t)b_own * TT + tq) * 512 + (tid & 511)];
        __syncthreads();
        f32x4 f = {0.f, 0.f, 0.f, 0.f};
        for (int k = 0; k < 512; ++k){
            float xv = xrow[k];
            #pragma unroll
            for (int j = 0; j < 4; ++j)
                f[j] += xv * Wfc[(size_t)(n0 + j) * 512 + k];
        }
        return f;
    };

    int pv = flags[NPRE] & 3;
    int t = NPRE + 1;

    while (t < TT){
        if (pv & 1){
            // all fired at t-1: hypothesis outputs valid while AF chain holds
            if (tid == 0) firstbad = TT;
            __syncthreads();
            int idx = t + tid;
            if (idx < TT && AF[idx] == 0) atomicMin(&firstbad, idx);
            __syncthreads();
            int h = firstbad;
            if (h == TT) return;
            f32x4 cs = *reinterpret_cast<const f32x4*>(colsum + n0);
            f32x4 ffv = load_ff(h);
            f32x4 m;
            #pragma unroll
            for (int k = 0; k < 4; ++k) m[k] = cs[k] + ffv[k];
            finish_step(m, h);
            pv = wait_vote(h);
            t = h + 1;
        } else if (pv & 2){
            f32x4 ffv = load_ff(t);
            f32x4 mb = *reinterpret_cast<const f32x4*>(memb + (size_t)b_own * NN + n0);
            f32x4 m;
            #pragma unroll
            for (int k = 0; k < 4; ++k) m[k] = 0.96f * mb[k] + ffv[k];
            finish_step(m, t);
            pv = wait_vote(t);
            ++t;
        } else {
            // mixed: dense split-K GEMM over spikes
            gbar();
            auto load_tile = [&](int kt, short8* pa, short8* pb){
                int k0 = kt * 64;
                #pragma unroll
                for (int j = 0; j < 2; ++j){
                    int chunk = w * 2 + j;
                    int row = chunk * 8 + l8;
                    const u16* ga = spk + (size_t)(my * 128 + row) * NN + acol + k0 + (l7 << 3);
                    pa[j] = *reinterpret_cast<const short8*>(ga);
                    const u16* gb = Bc + (size_t)(bn * 128 + row) * KREC + kstart + k0 + (l7 << 3);
                    pb[j] = *reinterpret_cast<const short8*>(gb);
                }
            };
            auto write_tile = [&](int sel, const short8* pa, const short8* pb){
                #pragma unroll
                for (int j = 0; j < 2; ++j){
                    int chunk = w * 2 + j;
                    int idx = chunk * 512 + l8 * 64 + ((l7 ^ l8) << 3);
                    *reinterpret_cast<short8*>(&Ab[sel][idx]) = pa[j];
                    *reinterpret_cast<short8*>(&Bb[sel][idx]) = pb[j];
                }
            };

            f32x4 zero = {0.f, 0.f, 0.f, 0.f};
            f32x4 acc[4][2];
            #pragma unroll
            for (int mi = 0; mi < 4; ++mi)
                #pragma unroll
                for (int ni = 0; ni < 2; ++ni) acc[mi][ni] = zero;

            short8 ra[2], rb[2], na[2], nb[2];
            load_tile(0, ra, rb);
            write_tile(0, ra, rb);
            __syncthreads();

            for (int kt = 0; kt < 8; ++kt){
                int sel = kt & 1;
                if (kt + 1 < 8) load_tile(kt + 1, na, nb);
                #pragma unroll
                for (int kk2 = 0; kk2 < 2; ++kk2){
                    int ke = kk2 * 32 + ((lane >> 4) << 3);
                    short8 af2[4], bfr[2];
                    #pragma unroll
                    for (int mi = 0; mi < 4; ++mi){
                        int row = wm * 64 + mi * 16 + (lane & 15);
                        int byte = (row * 128 + ke * 2) ^ ((row & 7) << 4);
                        af2[mi] = *reinterpret_cast<const short8*>(reinterpret_cast<const char*>(Ab[sel]) + byte);
                    }
                    #pragma unroll
                    for (int ni = 0; ni < 2; ++ni){
                        int row = wn * 32 + ni * 16 + (lane & 15);
                        int byte = (row * 128 + ke * 2) ^ ((row & 7) << 4);
                        bfr[ni] = *reinterpret_cast<const short8*>(reinterpret_cast<const char*>(Bb[sel]) + byte);
                    }
                    #pragma unroll
                    for (int mi = 0; mi < 4; ++mi)
                        #pragma unroll
                        for (int ni = 0; ni < 2; ++ni)
                            acc[mi][ni] = __builtin_amdgcn_mfma_f32_16x16x32_bf16(af2[mi], bfr[ni], acc[mi][ni], 0, 0, 0);
                }
                if (kt + 1 < 8) write_tile((kt + 1) & 1, na, nb);
                __syncthreads();
            }

            float* pp = part + (size_t)ks * (NB * NN);
            const int r4 = (lane >> 4) << 2;
            const int c  = lane & 15;
            #pragma unroll
            for (int mi = 0; mi < 4; ++mi)
                #pragma unroll
                for (int ni = 0; ni < 2; ++ni){
                    int n = bn * 128 + wn * 32 + ni * 16 + c;
                    #pragma unroll
                    for (int jj = 0; jj < 4; ++jj){
                        int b = my * 128 + wm * 64 + mi * 16 + r4 + jj;
                        pp[(size_t)b * NN + n] = acc[mi][ni][jj];
                    }
                }
            gbar();

            f32x4 ffv = load_ff(t);
            f32x4 mb = *reinterpret_cast<const f32x4*>(memb + (size_t)b_own * NN + n0);
            u16x4 sp = *reinterpret_cast<const u16x4*>(spk + (size_t)b_own * NN + n0);
            float p[4] = {0.f, 0.f, 0.f, 0.f};
            #pragma unroll
            for (int ks2 = 0; ks2 < 8; ++ks2){
                f32x4 pvv = *reinterpret_cast<const f32x4*>(part + (size_t)ks2 * (NB * NN) + (size_t)b_own * NN + n0);
                #pragma unroll
                for (int k = 0; k < 4; ++k) p[k] += pvv[k];
            }
            f32x4 m;
            #pragma unroll
            for (int k = 0; k < 4; ++k){
                float sprev = sp[k] ? 1.f : 0.f;
                m[k] = 0.96f * mb[k] * (1.f - sprev) + p[k] + ffv[k];
            }
            finish_step(m, t);
            pv = wait_vote(t);
            ++t;
        }
    }
}

// ---------------- host ----------------
extern "C" void kernel_launch(void* const* d_in, const int* in_sizes, int n_in,
                              void* d_out, int out_size, void* d_ws, size_t ws_size,
                              hipStream_t stream)
{
    const float* x   = (const float*)d_in[0];
    const float* Wfc = (const float*)d_in[1];
    const float* rec = (const float*)d_in[2];
    const float* msk = (const float*)d_in[3];
    const float* bin = (const float*)d_in[4];
    float* out = (float*)d_out;
    char* ws = (char*)d_ws;

    u16* Wh      = (u16*)(ws + OFF_WH);
    u16* Wl      = (u16*)(ws + OFF_WL);
    u16* xh4     = (u16*)(ws + OFF_XH4);
    u16* xl4     = (u16*)(ws + OFF_XL4);
    u16* Bc      = (u16*)(ws + OFF_BC);
    float* cs    = (float*)(ws + OFF_COLS);
    float* partc = (float*)(ws + OFF_PARTC);
    float* ffpre = (float*)(ws + OFF_FFPRE);
    u16* spk     = (u16*)(ws + OFF_SPK);
    float* memb  = (float*)(ws + OFF_MEMB);
    float* part  = (float*)(ws + OFF_PART);
    int* flags   = (int*)(ws + OFF_FLAGS);
    int* AF      = (int*)(ws + OFF_AF);
    int* sync    = (int*)(ws + OFF_SYNC);

    hipMemsetAsync(flags, 0xFF, 64, stream);
    hipMemsetAsync(AF, 0xFF, 512, stream);
    hipMemsetAsync(sync, 0, 1024, stream);

    prep_w<<<4096, 256, 0, stream>>>(Wfc, Wh, Wl);
    prep_x4<<<2048, 256, 0, stream>>>(x, xh4, xl4);
    prep_rec<<<dim3(32, 32), 256, 0, stream>>>(rec, msk, bin, Bc, partc);
    colsum2<<<8, 256, 0, stream>>>(partc, cs);
    ffpre_gemm<<<dim3(16, 8), 512, 0, stream>>>(xh4, xl4, Wh, Wl, ffpre);
    ff_hi_gemm<<<dim3(16, 200), 512, 0, stream>>>(x, Wh, cs, AF, out);
    lif0<<<256, 512, 0, stream>>>(ffpre, spk, memb, out, flags);
    for (int t = 1; t <= NPRE; ++t){
        gemm_pre<<<256, 512, 0, stream>>>(Bc, spk, flags, part, t);
        lif_pre<<<256, 512, 0, stream>>>(ffpre, cs, part, AF, spk, memb, out, flags, t);
    }
    snn_tail<<<256, 512, 0, stream>>>(Bc, x, Wfc, cs, AF, flags, spk, memb, part, sync, out);
}

// Round 5
// 178.038 us; speedup vs baseline: 15.9723x; 1.1442x over previous
//
#include <hip/hip_runtime.h>

typedef unsigned short u16;
typedef __attribute__((ext_vector_type(8))) short short8;
typedef __attribute__((ext_vector_type(4))) float f32x4;
typedef __attribute__((ext_vector_type(4))) unsigned short u16x4;

#define TT 100
#define NB 256
#define NN 2048
#define KREC 4096
#define NPRE 3
#define EPS 0.25f

// ws layout (bytes); total ~76.8 MB
#define OFF_WH    0ull            // bf16 [2048][512]      2097152
#define OFF_WL    2097152ull      // bf16 [2048][512]      2097152
#define OFF_XALL  4194304ull      // bf16 [100][256][512] 26214400
#define OFF_XL4   30408704ull     // bf16 [4][256][512]    1048576
#define OFF_BC    31457280ull     // bf16 [2048][4096]    16777216
#define OFF_COLS  48234496ull     // fp32 [2048]              8192
#define OFF_PARTC 48242688ull     // fp32 [32][2048]        262144
#define OFF_FFPRE 48504832ull     // fp32 [4][256][2048]   8388608
#define OFF_SPK   56893440ull     // bf16 [256][2048]      1048576
#define OFF_MEMB  57942016ull     // fp32 [256][2048]      2097152
#define OFF_PART  60039168ull     // fp32 [8][256][2048]  16777216
#define OFF_FLAGS 76816384ull     // int flags[16]
#define OFF_AF    76816448ull     // int AF[100+pad]
#define OFF_SYNC  76816960ull     // int cnt, gen, vote[100]

__device__ __forceinline__ u16 f2bf(float f){
    unsigned int x = __float_as_uint(f);
    x += 0x7fffu + ((x >> 16) & 1u);          // RNE to bf16
    return (u16)(x >> 16);
}
__device__ __forceinline__ float bf2f(u16 u){
    return __uint_as_float(((unsigned int)u) << 16);
}

// ---------------- prep kernels ----------------

__global__ void prep_w(const float* __restrict__ Wfc, u16* __restrict__ Wh, u16* __restrict__ Wl){
    int idx = blockIdx.x * 256 + threadIdx.x;      // 1,048,576
    float v = Wfc[idx];
    u16 h = f2bf(v);
    Wh[idx] = h;
    Wl[idx] = f2bf(v - bf2f(h));
}

// x [b][t][512] fp32 -> xall [(t*256+b)][512] bf16 (hoisted conversion, done ONCE)
__global__ void x_to_bf(const float* __restrict__ x, u16* __restrict__ xall){
    int idx = blockIdx.x * 256 + threadIdx.x;      // 1,638,400 threads x 8 elems
    int b = idx / (TT * 64);
    int r = idx - b * (TT * 64);
    int t = r >> 6;
    int c = r & 63;
    const float* gx = x + ((size_t)b * TT + t) * 512 + (c << 3);
    f32x4 f0 = *reinterpret_cast<const f32x4*>(gx);
    f32x4 f1 = *reinterpret_cast<const f32x4*>(gx + 4);
    short8 v;
    #pragma unroll
    for (int i = 0; i < 4; ++i){
        v[i]     = (short)f2bf(f0[i]);
        v[i + 4] = (short)f2bf(f1[i]);
    }
    *reinterpret_cast<short8*>(xall + ((size_t)t * NB + b) * 512 + (c << 3)) = v;
}

// lo residuals for t=0..3 (exact prefix ff)
__global__ void prep_xl4(const float* __restrict__ x, u16* __restrict__ xl){
    int idx = blockIdx.x * 256 + threadIdx.x;      // 524,288 = 4*256*512
    int t = idx >> 17;
    int r = idx & 131071;
    int b = r >> 9;
    int i = r & 511;
    float v = x[((size_t)b * TT + t) * 512 + i];
    u16 h = f2bf(v);
    xl[((size_t)t * NB + b) * 512 + i] = f2bf(v - bf2f(h));
}

// eff_rec transpose+split into Bc, plus deterministic colsum partials
__global__ void prep_rec(const float* __restrict__ rec, const float* __restrict__ msk,
                         const float* __restrict__ bin, u16* __restrict__ Bc,
                         float* __restrict__ partc){
    __shared__ u16 hs[64][66];
    __shared__ u16 ls[64][66];
    __shared__ float redc[4][64];
    int tid = threadIdx.x;
    int tm = tid & 63, t4 = tid >> 6;
    int m0 = blockIdx.x * 64, n0 = blockIdx.y * 64;
    float accl = 0.f;
    #pragma unroll
    for (int j = 0; j < 16; ++j){
        int nl = t4 + j * 4;
        size_t gi = (size_t)(n0 + nl) * NN + m0 + tm;
        float e = rec[gi] * msk[gi] * bin[gi];
        u16 h = f2bf(e);
        hs[nl][tm] = h;
        ls[nl][tm] = f2bf(e - bf2f(h));
        accl += e;
    }
    redc[t4][tm] = accl;
    __syncthreads();
    if (t4 == 0)
        partc[(size_t)blockIdx.y * NN + m0 + tm] =
            redc[0][tm] + redc[1][tm] + redc[2][tm] + redc[3][tm];
    #pragma unroll
    for (int j = 0; j < 16; ++j){
        int ml = t4 + j * 4;
        size_t o = (size_t)(m0 + ml) * KREC + n0 + tm;
        Bc[o]        = hs[tm][ml];
        Bc[o + 2048] = ls[tm][ml];
    }
}

__global__ void colsum2(const float* __restrict__ partc, float* __restrict__ cs){
    int j = blockIdx.x * 256 + threadIdx.x;   // 2048
    float s = 0.f;
    #pragma unroll
    for (int c = 0; c < 32; ++c) s += partc[(size_t)c * NN + j];
    cs[j] = s;
}

// ---------------- exact ff for t=0..NPRE: [xh|xh|xl].[Wh|Wl|Wh]^T, K=1536 ----------------
__global__ __launch_bounds__(512, 2) void ffpre_gemm(const u16* __restrict__ xall,
    const u16* __restrict__ xl4, const u16* __restrict__ Wh, const u16* __restrict__ Wl,
    float* __restrict__ ffpre)
{
    __shared__ u16 Ab[2][8192];
    __shared__ u16 Bb[2][8192];
    const int tid = threadIdx.x, lane = tid & 63, w = tid >> 6;
    const int l7 = lane & 7, l8 = lane >> 3;
    const int bn = blockIdx.x;       // 16
    const int mt = blockIdx.y;       // 8  (M = 4*256)
    const int wm = w >> 2, wn = w & 3;

    auto load_tile = [&](int kt, short8* pa, short8* pb){
        int k0 = kt * 64;
        int reg = k0 >> 9;
        int kk = k0 & 511;
        const u16* ab = (reg == 2) ? xl4 : xall;
        const u16* bb2 = (reg == 1) ? Wl : Wh;
        #pragma unroll
        for (int j = 0; j < 2; ++j){
            int chunk = w * 2 + j;
            int row = chunk * 8 + l8;
            pa[j] = *reinterpret_cast<const short8*>(ab + (size_t)(mt * 128 + row) * 512 + kk + (l7 << 3));
            pb[j] = *reinterpret_cast<const short8*>(bb2 + (size_t)(bn * 128 + row) * 512 + kk + (l7 << 3));
        }
    };
    auto write_tile = [&](int sel, const short8* pa, const short8* pb){
        #pragma unroll
        for (int j = 0; j < 2; ++j){
            int chunk = w * 2 + j;
            int idx = chunk * 512 + l8 * 64 + ((l7 ^ l8) << 3);
            *reinterpret_cast<short8*>(&Ab[sel][idx]) = pa[j];
            *reinterpret_cast<short8*>(&Bb[sel][idx]) = pb[j];
        }
    };

    f32x4 zero = {0.f, 0.f, 0.f, 0.f};
    f32x4 acc[4][2];
    #pragma unroll
    for (int mi = 0; mi < 4; ++mi)
        #pragma unroll
        for (int ni = 0; ni < 2; ++ni) acc[mi][ni] = zero;

    short8 ra[2], rb[2], na[2], nb[2];
    load_tile(0, ra, rb);
    write_tile(0, ra, rb);
    __syncthreads();

    for (int kt = 0; kt < 24; ++kt){
        int sel = kt & 1;
        if (kt + 1 < 24) load_tile(kt + 1, na, nb);
        #pragma unroll
        for (int kk2 = 0; kk2 < 2; ++kk2){
            int ke = kk2 * 32 + ((lane >> 4) << 3);
            short8 af[4], bfr[2];
            #pragma unroll
            for (int mi = 0; mi < 4; ++mi){
                int row = wm * 64 + mi * 16 + (lane & 15);
                int byte = (row * 128 + ke * 2) ^ ((row & 7) << 4);
                af[mi] = *reinterpret_cast<const short8*>(reinterpret_cast<const char*>(Ab[sel]) + byte);
            }
            #pragma unroll
            for (int ni = 0; ni < 2; ++ni){
                int row = wn * 32 + ni * 16 + (lane & 15);
                int byte = (row * 128 + ke * 2) ^ ((row & 7) << 4);
                bfr[ni] = *reinterpret_cast<const short8*>(reinterpret_cast<const char*>(Bb[sel]) + byte);
            }
            #pragma unroll
            for (int mi = 0; mi < 4; ++mi)
                #pragma unroll
                for (int ni = 0; ni < 2; ++ni)
                    acc[mi][ni] = __builtin_amdgcn_mfma_f32_16x16x32_bf16(af[mi], bfr[ni], acc[mi][ni], 0, 0, 0);
        }
        if (kt + 1 < 24) write_tile((kt + 1) & 1, na, nb);
        __syncthreads();
    }

    const int r4 = (lane >> 4) << 2;
    const int c  = lane & 15;
    #pragma unroll
    for (int mi = 0; mi < 4; ++mi)
        #pragma unroll
        for (int ni = 0; ni < 2; ++ni){
            int n = bn * 128 + wn * 32 + ni * 16 + c;
            #pragma unroll
            for (int jj = 0; jj < 4; ++jj){
                int m = mt * 128 + wm * 64 + mi * 16 + r4 + jj;
                ffpre[(size_t)m * NN + n] = acc[mi][ni][jj];
            }
        }
}

// ---------------- hypothesis GEMM: validate AF[t] + write hypothesis readouts ----------------
// A = xall (pre-converted bf16). 1-D grid 3200, XCD-chunked swizzle: all 16 bn-blocks
// of one mt land on the SAME XCD -> A-tile fetched from HBM once, L2-served after.
__global__ __launch_bounds__(512, 2) void ff_hi_gemm(const u16* __restrict__ xall,
    const u16* __restrict__ Wh, const float* __restrict__ colsum,
    int* __restrict__ AF, float* __restrict__ out)
{
    __shared__ u16 Ab[2][8192];
    __shared__ u16 Bb[2][8192];
    __shared__ int redH[8];
    const int tid = threadIdx.x, lane = tid & 63, w = tid >> 6;
    const int l7 = lane & 7, l8 = lane >> 3;
    const int bid = blockIdx.x;                 // 3200 = 8 XCDs * 400
    const int logical = (bid & 7) * 400 + (bid >> 3);
    const int mt = logical >> 4;                // 0..199
    const int bn = logical & 15;                // 0..15
    const int wm = w >> 2, wn = w & 3;

    auto load_tile = [&](int kt, short8* pa, short8* pb){
        int k0 = kt * 64;
        #pragma unroll
        for (int j = 0; j < 2; ++j){
            int chunk = w * 2 + j;
            int row = chunk * 8 + l8;
            pa[j] = *reinterpret_cast<const short8*>(xall + (size_t)(mt * 128 + row) * 512 + k0 + (l7 << 3));
            pb[j] = *reinterpret_cast<const short8*>(Wh + (size_t)(bn * 128 + row) * 512 + k0 + (l7 << 3));
        }
    };
    auto write_tile = [&](int sel, const short8* pa, const short8* pb){
        #pragma unroll
        for (int j = 0; j < 2; ++j){
            int chunk = w * 2 + j;
            int idx = chunk * 512 + l8 * 64 + ((l7 ^ l8) << 3);
            *reinterpret_cast<short8*>(&Ab[sel][idx]) = pa[j];
            *reinterpret_cast<short8*>(&Bb[sel][idx]) = pb[j];
        }
    };

    f32x4 zero = {0.f, 0.f, 0.f, 0.f};
    f32x4 acc[4][2];
    #pragma unroll
    for (int mi = 0; mi < 4; ++mi)
        #pragma unroll
        for (int ni = 0; ni < 2; ++ni) acc[mi][ni] = zero;

    short8 ra[2], rb[2], na[2], nb[2];
    load_tile(0, ra, rb);
    write_tile(0, ra, rb);
    __syncthreads();

    for (int kt = 0; kt < 8; ++kt){
        int sel = kt & 1;
        if (kt + 1 < 8) load_tile(kt + 1, na, nb);
        #pragma unroll
        for (int kk2 = 0; kk2 < 2; ++kk2){
            int ke = kk2 * 32 + ((lane >> 4) << 3);
            short8 af[4], bfr[2];
            #pragma unroll
            for (int mi = 0; mi < 4; ++mi){
                int row = wm * 64 + mi * 16 + (lane & 15);
                int byte = (row * 128 + ke * 2) ^ ((row & 7) << 4);
                af[mi] = *reinterpret_cast<const short8*>(reinterpret_cast<const char*>(Ab[sel]) + byte);
            }
            #pragma unroll
            for (int ni = 0; ni < 2; ++ni){
                int row = wn * 32 + ni * 16 + (lane & 15);
                int byte = (row * 128 + ke * 2) ^ ((row & 7) << 4);
                bfr[ni] = *reinterpret_cast<const short8*>(reinterpret_cast<const char*>(Bb[sel]) + byte);
            }
            #pragma unroll
            for (int mi = 0; mi < 4; ++mi)
                #pragma unroll
                for (int ni = 0; ni < 2; ++ni)
                    acc[mi][ni] = __builtin_amdgcn_mfma_f32_16x16x32_bf16(af[mi], bfr[ni], acc[mi][ni], 0, 0, 0);
        }
        if (kt + 1 < 8) write_tile((kt + 1) & 1, na, nb);
        __syncthreads();
    }

    const int r4 = (lane >> 4) << 2;
    const int c  = lane & 15;
    const int t_out = mt >> 1;
    int ok = 1;
    float cs0 = colsum[bn * 128 + wn * 32 + c];
    float cs1 = colsum[bn * 128 + wn * 32 + 16 + c];
    #pragma unroll
    for (int mi = 0; mi < 4; ++mi)
        #pragma unroll
        for (int ni = 0; ni < 2; ++ni){
            int n = bn * 128 + wn * 32 + ni * 16 + c;
            float csv = ni ? cs1 : cs0;
            #pragma unroll
            for (int jj = 0; jj < 4; ++jj){
                int m = mt * 128 + wm * 64 + mi * 16 + r4 + jj;
                float v = acc[mi][ni][jj] + csv;
                ok &= (v >= 1.0f + EPS) ? 1 : 0;      // fire with margin
                if (bn == 15 && n >= 2000){
                    int b = m & 255;
                    out[((size_t)b * TT + t_out) * 48 + (n - 2000)] = (v >= 1.0f) ? 1.f : 0.f;
                }
            }
        }
    unsigned long long bb = __ballot(ok != 0);
    if (lane == 0) redH[w] = (bb == ~0ull) ? 1 : 0;
    __syncthreads();
    if (tid == 0){
        int a = 1;
        #pragma unroll
        for (int i = 0; i < 8; ++i) a &= redH[i];
        atomicAnd(&AF[t_out], a ? ~0 : 0);
    }
}

// ---------------- prefix LIF kernels (stream-ordered; kernel boundary = sync) ----------------
// verdict bits: 1 = all fired, 2 = all zero, 0 = mixed

__device__ __forceinline__ void lif_finish(int b, int n0, const float mem[4], int t,
    u16* __restrict__ spk, float* __restrict__ memb, float* __restrict__ out,
    int* __restrict__ flags, int* red, int tid, int lane, int w)
{
    int s[4];
    u16x4 sv; f32x4 mv;
    #pragma unroll
    for (int k = 0; k < 4; ++k){
        s[k] = (mem[k] >= 1.0f) ? 1 : 0;
        sv[k] = s[k] ? (u16)0x3F80 : (u16)0;
        mv[k] = mem[k];
    }
    *reinterpret_cast<u16x4*>(spk + (size_t)b * NN + n0) = sv;
    *reinterpret_cast<f32x4*>(memb + (size_t)b * NN + n0) = mv;
    if (n0 >= 2000){
        #pragma unroll
        for (int k = 0; k < 4; ++k)
            out[((size_t)b * TT + t) * 48 + (n0 + k - 2000)] = s[k] ? 1.f : 0.f;
    }
    int af = s[0] & s[1] & s[2] & s[3];
    int az = !(s[0] | s[1] | s[2] | s[3]);
    unsigned long long ba = __ballot(af != 0);
    unsigned long long bz = __ballot(az != 0);
    if (lane == 0) red[w] = ((ba == ~0ull) ? 1 : 0) | ((bz == ~0ull) ? 2 : 0);
    __syncthreads();
    if (tid == 0){
        int a = 3;
        #pragma unroll
        for (int i = 0; i < 8; ++i) a &= red[i];
        atomicAnd(&flags[t], 0xFFFFFFFC | a);
    }
}

// t=0: mem = ff (exact), spikes/mem all-zero init guaranteed
__global__ __launch_bounds__(512) void lif0(const float* __restrict__ ffpre,
    u16* __restrict__ spk, float* __restrict__ memb, float* __restrict__ out,
    int* __restrict__ flags)
{
    __shared__ int red[8];
    const int tid = threadIdx.x, lane = tid & 63, w = tid >> 6;
    const int b = blockIdx.x, n0 = tid << 2;
    f32x4 fe = *reinterpret_cast<const f32x4*>(ffpre + (size_t)b * NN + n0);
    float m[4];
    #pragma unroll
    for (int k = 0; k < 4; ++k) m[k] = fe[k];
    lif_finish(b, n0, m, 0, spk, memb, out, flags, red, tid, lane, w);
}

// dense split-K GEMM over spikes; skipped unless flag[t-1] == mixed
__global__ __launch_bounds__(512, 2) void gemm_pre(
    const u16* __restrict__ Bc, const u16* __restrict__ spk,
    const int* __restrict__ flags, float* __restrict__ part, int t)
{
    if (flags[t - 1] & 3) return;
    __shared__ u16 Ab[2][8192];
    __shared__ u16 Bb[2][8192];
    const int tid = threadIdx.x, lane = tid & 63, w = tid >> 6;
    const int l7 = lane & 7, l8 = lane >> 3;
    const int bid = blockIdx.x;
    const int bn = bid & 15, my = (bid >> 4) & 1, ks = bid >> 5;
    const int kstart = ks << 9, acol = kstart & 2047;
    const int wm = w >> 2, wn = w & 3;

    auto load_tile = [&](int kt, short8* pa, short8* pb){
        int k0 = kt * 64;
        #pragma unroll
        for (int j = 0; j < 2; ++j){
            int chunk = w * 2 + j;
            int row = chunk * 8 + l8;
            const u16* ga = spk + (size_t)(my * 128 + row) * NN + acol + k0 + (l7 << 3);
            pa[j] = *reinterpret_cast<const short8*>(ga);
            const u16* gb = Bc + (size_t)(bn * 128 + row) * KREC + kstart + k0 + (l7 << 3);
            pb[j] = *reinterpret_cast<const short8*>(gb);
        }
    };
    auto write_tile = [&](int sel, const short8* pa, const short8* pb){
        #pragma unroll
        for (int j = 0; j < 2; ++j){
            int chunk = w * 2 + j;
            int idx = chunk * 512 + l8 * 64 + ((l7 ^ l8) << 3);
            *reinterpret_cast<short8*>(&Ab[sel][idx]) = pa[j];
            *reinterpret_cast<short8*>(&Bb[sel][idx]) = pb[j];
        }
    };

    f32x4 zero = {0.f, 0.f, 0.f, 0.f};
    f32x4 acc[4][2];
    #pragma unroll
    for (int mi = 0; mi < 4; ++mi)
        #pragma unroll
        for (int ni = 0; ni < 2; ++ni) acc[mi][ni] = zero;

    short8 ra[2], rb[2], na[2], nb[2];
    load_tile(0, ra, rb);
    write_tile(0, ra, rb);
    __syncthreads();

    for (int kt = 0; kt < 8; ++kt){
        int sel = kt & 1;
        if (kt + 1 < 8) load_tile(kt + 1, na, nb);
        #pragma unroll
        for (int kk2 = 0; kk2 < 2; ++kk2){
            int ke = kk2 * 32 + ((lane >> 4) << 3);
            short8 af2[4], bfr[2];
            #pragma unroll
            for (int mi = 0; mi < 4; ++mi){
                int row = wm * 64 + mi * 16 + (lane & 15);
                int byte = (row * 128 + ke * 2) ^ ((row & 7) << 4);
                af2[mi] = *reinterpret_cast<const short8*>(reinterpret_cast<const char*>(Ab[sel]) + byte);
            }
            #pragma unroll
            for (int ni = 0; ni < 2; ++ni){
                int row = wn * 32 + ni * 16 + (lane & 15);
                int byte = (row * 128 + ke * 2) ^ ((row & 7) << 4);
                bfr[ni] = *reinterpret_cast<const short8*>(reinterpret_cast<const char*>(Bb[sel]) + byte);
            }
            #pragma unroll
            for (int mi = 0; mi < 4; ++mi)
                #pragma unroll
                for (int ni = 0; ni < 2; ++ni)
                    acc[mi][ni] = __builtin_amdgcn_mfma_f32_16x16x32_bf16(af2[mi], bfr[ni], acc[mi][ni], 0, 0, 0);
        }
        if (kt + 1 < 8) write_tile((kt + 1) & 1, na, nb);
        __syncthreads();
    }

    float* pp = part + (size_t)ks * (NB * NN);
    const int r4 = (lane >> 4) << 2;
    const int c  = lane & 15;
    #pragma unroll
    for (int mi = 0; mi < 4; ++mi)
        #pragma unroll
        for (int ni = 0; ni < 2; ++ni){
            int n = bn * 128 + wn * 32 + ni * 16 + c;
            #pragma unroll
            for (int jj = 0; jj < 4; ++jj){
                int b = my * 128 + wm * 64 + mi * 16 + r4 + jj;
                pp[(size_t)b * NN + n] = acc[mi][ni][jj];
            }
        }
}

// LIF for step t in [1, NPRE]
__global__ __launch_bounds__(512) void lif_pre(const float* __restrict__ ffpre,
    const float* __restrict__ colsum, const float* __restrict__ part,
    const int* __restrict__ AF, u16* __restrict__ spk, float* __restrict__ memb,
    float* __restrict__ out, int* __restrict__ flags, int t)
{
    __shared__ int red[8];
    const int tid = threadIdx.x, lane = tid & 63, w = tid >> 6;
    const int b = blockIdx.x, n0 = tid << 2;
    int fl = flags[t - 1] & 3;
    float m[4];

    if (fl & 1){
        if (AF[t] != 0){                      // chain holds: hypothesis out[t] valid
            if (b == 0 && tid == 0) flags[t] = 1;
            return;
        }
        // AF break: materialize exactly (all fired at t-1 -> mem = colsum + ff)
        f32x4 cs = *reinterpret_cast<const f32x4*>(colsum + n0);
        f32x4 fe = *reinterpret_cast<const f32x4*>(ffpre + ((size_t)t * NB + b) * NN + n0);
        #pragma unroll
        for (int k = 0; k < 4; ++k) m[k] = cs[k] + fe[k];
    } else if (fl & 2){
        f32x4 mb = *reinterpret_cast<const f32x4*>(memb + (size_t)b * NN + n0);
        f32x4 fe = *reinterpret_cast<const f32x4*>(ffpre + ((size_t)t * NB + b) * NN + n0);
        #pragma unroll
        for (int k = 0; k < 4; ++k) m[k] = 0.96f * mb[k] + fe[k];
    } else {
        f32x4 mb = *reinterpret_cast<const f32x4*>(memb + (size_t)b * NN + n0);
        u16x4 sp = *reinterpret_cast<const u16x4*>(spk + (size_t)b * NN + n0);
        f32x4 fe = *reinterpret_cast<const f32x4*>(ffpre + ((size_t)t * NB + b) * NN + n0);
        float p[4] = {0.f, 0.f, 0.f, 0.f};
        #pragma unroll
        for (int ks2 = 0; ks2 < 8; ++ks2){
            f32x4 pv = *reinterpret_cast<const f32x4*>(part + (size_t)ks2 * (NB * NN) + (size_t)b * NN + n0);
            #pragma unroll
            for (int k = 0; k < 4; ++k) p[k] += pv[k];
        }
        #pragma unroll
        for (int k = 0; k < 4; ++k){
            float sprev = sp[k] ? 1.f : 0.f;
            m[k] = 0.96f * mb[k] * (1.f - sprev) + p[k] + fe[k];
        }
    }
    lif_finish(b, n0, m, t, spk, memb, out, flags, red, tid, lane, w);
}

// ---------------- persistent tail: t in [NPRE+1, TT) ----------------
__global__ __launch_bounds__(512, 1) void snn_tail(
    const u16* __restrict__ Bc, const float* __restrict__ x, const float* __restrict__ Wfc,
    const float* __restrict__ colsum, const int* __restrict__ AF, const int* __restrict__ flags,
    u16* __restrict__ spk, float* __restrict__ memb, float* __restrict__ part,
    int* __restrict__ sync, float* __restrict__ out)
{
    __shared__ u16 Ab[2][8192];
    __shared__ u16 Bb[2][8192];
    __shared__ float xrow[512];
    __shared__ int red[8];
    __shared__ int bcast;
    __shared__ int firstbad;
    const int tid = threadIdx.x, lane = tid & 63, w = tid >> 6;
    const int l7 = lane & 7, l8 = lane >> 3;
    const int bid = blockIdx.x;
    int* cnt = sync;
    int* gen = sync + 1;
    int* vote = sync + 2;
    const int b_own = bid;
    const int n0 = tid << 2;
    const int bn = bid & 15, my = (bid >> 4) & 1, ks = bid >> 5;
    const int kstart = ks << 9, acol = kstart & 2047;
    const int wm = w >> 2, wn = w & 3;

    auto gbar = [&](){
        asm volatile("s_waitcnt vmcnt(0) lgkmcnt(0)" ::: "memory");
        __syncthreads();
        if (tid == 0){
            __threadfence();
            int g = __hip_atomic_load(gen, __ATOMIC_RELAXED, __HIP_MEMORY_SCOPE_AGENT);
            int a = __hip_atomic_fetch_add(cnt, 1, __ATOMIC_ACQ_REL, __HIP_MEMORY_SCOPE_AGENT);
            if (a == (int)gridDim.x - 1){
                __hip_atomic_store(cnt, 0, __ATOMIC_RELAXED, __HIP_MEMORY_SCOPE_AGENT);
                __hip_atomic_fetch_add(gen, 1, __ATOMIC_RELEASE, __HIP_MEMORY_SCOPE_AGENT);
            } else {
                while (__hip_atomic_load(gen, __ATOMIC_ACQUIRE, __HIP_MEMORY_SCOPE_AGENT) == g)
                    __builtin_amdgcn_s_sleep(2);
            }
            __threadfence();
        }
        __syncthreads();
    };

    auto wait_vote = [&](int t)->int{
        if (tid == 0){
            int v;
            while (((unsigned)(v = __hip_atomic_load(&vote[t], __ATOMIC_ACQUIRE, __HIP_MEMORY_SCOPE_AGENT)) >> 20) != 256u)
                __builtin_amdgcn_s_sleep(2);
            bcast = v;
        }
        __syncthreads();
        int v = bcast;
        __syncthreads();
        int naf = ((v & 0x3FF) == 256) ? 1 : 0;
        int naz = (((v >> 10) & 0x3FF) == 256) ? 2 : 0;
        return naf | naz;
    };

    auto finish_step = [&](f32x4 m, int t){
        int s[4];
        u16x4 sv;
        #pragma unroll
        for (int k = 0; k < 4; ++k){
            s[k] = (m[k] >= 1.0f) ? 1 : 0;
            sv[k] = s[k] ? (u16)0x3F80 : (u16)0;
        }
        *reinterpret_cast<u16x4*>(spk + (size_t)b_own * NN + n0) = sv;
        *reinterpret_cast<f32x4*>(memb + (size_t)b_own * NN + n0) = m;
        if (n0 >= 2000){
            #pragma unroll
            for (int k = 0; k < 4; ++k)
                out[((size_t)b_own * TT + t) * 48 + (n0 + k - 2000)] = s[k] ? 1.f : 0.f;
        }
        int af = s[0] & s[1] & s[2] & s[3];
        int az = !(s[0] | s[1] | s[2] | s[3]);
        unsigned long long ba = __ballot(af != 0);
        unsigned long long bz = __ballot(az != 0);
        if (lane == 0) red[w] = ((ba == ~0ull) ? 1 : 0) | ((bz == ~0ull) ? 2 : 0);
        __syncthreads();
        if (tid == 0){
            int a = 3;
            #pragma unroll
            for (int i = 0; i < 8; ++i) a &= red[i];
            __hip_atomic_fetch_add(&vote[t], (1 << 20) | (a & 1) | ((a >> 1) << 10),
                                   __ATOMIC_RELEASE, __HIP_MEMORY_SCOPE_AGENT);
        }
        __syncthreads();
    };

    // exact fp32 on-the-fly ff for this block's batch row (cold path only)
    auto load_ff = [&](int tq)->f32x4{
        __syncthreads();
        xrow[tid & 511] = x[((size_t)b_own * TT + tq) * 512 + (tid & 511)];
        __syncthreads();
        f32x4 f = {0.f, 0.f, 0.f, 0.f};
        for (int k = 0; k < 512; ++k){
            float xv = xrow[k];
            #pragma unroll
            for (int j = 0; j < 4; ++j)
                f[j] += xv * Wfc[(size_t)(n0 + j) * 512 + k];
        }
        return f;
    };

    int pv = flags[NPRE] & 3;
    int t = NPRE + 1;

    while (t < TT){
        if (pv & 1){
            // all fired at t-1: hypothesis outputs valid while AF chain holds
            if (tid == 0) firstbad = TT;
            __syncthreads();
            int idx = t + tid;
            if (idx < TT && AF[idx] == 0) atomicMin(&firstbad, idx);
            __syncthreads();
            int h = firstbad;
            if (h == TT) return;
            f32x4 cs = *reinterpret_cast<const f32x4*>(colsum + n0);
            f32x4 ffv = load_ff(h);
            f32x4 m;
            #pragma unroll
            for (int k = 0; k < 4; ++k) m[k] = cs[k] + ffv[k];
            finish_step(m, h);
            pv = wait_vote(h);
            t = h + 1;
        } else if (pv & 2){
            f32x4 ffv = load_ff(t);
            f32x4 mb = *reinterpret_cast<const f32x4*>(memb + (size_t)b_own * NN + n0);
            f32x4 m;
            #pragma unroll
            for (int k = 0; k < 4; ++k) m[k] = 0.96f * mb[k] + ffv[k];
            finish_step(m, t);
            pv = wait_vote(t);
            ++t;
        } else {
            // mixed: dense split-K GEMM over spikes
            gbar();
            auto load_tile = [&](int kt, short8* pa, short8* pb){
                int k0 = kt * 64;
                #pragma unroll
                for (int j = 0; j < 2; ++j){
                    int chunk = w * 2 + j;
                    int row = chunk * 8 + l8;
                    const u16* ga = spk + (size_t)(my * 128 + row) * NN + acol + k0 + (l7 << 3);
                    pa[j] = *reinterpret_cast<const short8*>(ga);
                    const u16* gb = Bc + (size_t)(bn * 128 + row) * KREC + kstart + k0 + (l7 << 3);
                    pb[j] = *reinterpret_cast<const short8*>(gb);
                }
            };
            auto write_tile = [&](int sel, const short8* pa, const short8* pb){
                #pragma unroll
                for (int j = 0; j < 2; ++j){
                    int chunk = w * 2 + j;
                    int idx = chunk * 512 + l8 * 64 + ((l7 ^ l8) << 3);
                    *reinterpret_cast<short8*>(&Ab[sel][idx]) = pa[j];
                    *reinterpret_cast<short8*>(&Bb[sel][idx]) = pb[j];
                }
            };

            f32x4 zero = {0.f, 0.f, 0.f, 0.f};
            f32x4 acc[4][2];
            #pragma unroll
            for (int mi = 0; mi < 4; ++mi)
                #pragma unroll
                for (int ni = 0; ni < 2; ++ni) acc[mi][ni] = zero;

            short8 ra[2], rb[2], na[2], nb[2];
            load_tile(0, ra, rb);
            write_tile(0, ra, rb);
            __syncthreads();

            for (int kt = 0; kt < 8; ++kt){
                int sel = kt & 1;
                if (kt + 1 < 8) load_tile(kt + 1, na, nb);
                #pragma unroll
                for (int kk2 = 0; kk2 < 2; ++kk2){
                    int ke = kk2 * 32 + ((lane >> 4) << 3);
                    short8 af2[4], bfr[2];
                    #pragma unroll
                    for (int mi = 0; mi < 4; ++mi){
                        int row = wm * 64 + mi * 16 + (lane & 15);
                        int byte = (row * 128 + ke * 2) ^ ((row & 7) << 4);
                        af2[mi] = *reinterpret_cast<const short8*>(reinterpret_cast<const char*>(Ab[sel]) + byte);
                    }
                    #pragma unroll
                    for (int ni = 0; ni < 2; ++ni){
                        int row = wn * 32 + ni * 16 + (lane & 15);
                        int byte = (row * 128 + ke * 2) ^ ((row & 7) << 4);
                        bfr[ni] = *reinterpret_cast<const short8*>(reinterpret_cast<const char*>(Bb[sel]) + byte);
                    }
                    #pragma unroll
                    for (int mi = 0; mi < 4; ++mi)
                        #pragma unroll
                        for (int ni = 0; ni < 2; ++ni)
                            acc[mi][ni] = __builtin_amdgcn_mfma_f32_16x16x32_bf16(af2[mi], bfr[ni], acc[mi][ni], 0, 0, 0);
                }
                if (kt + 1 < 8) write_tile((kt + 1) & 1, na, nb);
                __syncthreads();
            }

            float* pp = part + (size_t)ks * (NB * NN);
            const int r4 = (lane >> 4) << 2;
            const int c  = lane & 15;
            #pragma unroll
            for (int mi = 0; mi < 4; ++mi)
                #pragma unroll
                for (int ni = 0; ni < 2; ++ni){
                    int n = bn * 128 + wn * 32 + ni * 16 + c;
                    #pragma unroll
                    for (int jj = 0; jj < 4; ++jj){
                        int b = my * 128 + wm * 64 + mi * 16 + r4 + jj;
                        pp[(size_t)b * NN + n] = acc[mi][ni][jj];
                    }
                }
            gbar();

            f32x4 ffv = load_ff(t);
            f32x4 mb = *reinterpret_cast<const f32x4*>(memb + (size_t)b_own * NN + n0);
            u16x4 sp = *reinterpret_cast<const u16x4*>(spk + (size_t)b_own * NN + n0);
            float p[4] = {0.f, 0.f, 0.f, 0.f};
            #pragma unroll
            for (int ks2 = 0; ks2 < 8; ++ks2){
                f32x4 pvv = *reinterpret_cast<const f32x4*>(part + (size_t)ks2 * (NB * NN) + (size_t)b_own * NN + n0);
                #pragma unroll
                for (int k = 0; k < 4; ++k) p[k] += pvv[k];
            }
            f32x4 m;
            #pragma unroll
            for (int k = 0; k < 4; ++k){
                float sprev = sp[k] ? 1.f : 0.f;
                m[k] = 0.96f * mb[k] * (1.f - sprev) + p[k] + ffv[k];
            }
            finish_step(m, t);
            pv = wait_vote(t);
            ++t;
        }
    }
}

// ---------------- host ----------------
extern "C" void kernel_launch(void* const* d_in, const int* in_sizes, int n_in,
                              void* d_out, int out_size, void* d_ws, size_t ws_size,
                              hipStream_t stream)
{
    const float* x   = (const float*)d_in[0];
    const float* Wfc = (const float*)d_in[1];
    const float* rec = (const float*)d_in[2];
    const float* msk = (const float*)d_in[3];
    const float* bin = (const float*)d_in[4];
    float* out = (float*)d_out;
    char* ws = (char*)d_ws;

    u16* Wh      = (u16*)(ws + OFF_WH);
    u16* Wl      = (u16*)(ws + OFF_WL);
    u16* xall    = (u16*)(ws + OFF_XALL);
    u16* xl4     = (u16*)(ws + OFF_XL4);
    u16* Bc      = (u16*)(ws + OFF_BC);
    float* cs    = (float*)(ws + OFF_COLS);
    float* partc = (float*)(ws + OFF_PARTC);
    float* ffpre = (float*)(ws + OFF_FFPRE);
    u16* spk     = (u16*)(ws + OFF_SPK);
    float* memb  = (float*)(ws + OFF_MEMB);
    float* part  = (float*)(ws + OFF_PART);
    int* flags   = (int*)(ws + OFF_FLAGS);
    int* AF      = (int*)(ws + OFF_AF);
    int* sync    = (int*)(ws + OFF_SYNC);

    hipMemsetAsync(flags, 0xFF, 64, stream);
    hipMemsetAsync(AF, 0xFF, 512, stream);
    hipMemsetAsync(sync, 0, 1024, stream);

    prep_w<<<4096, 256, 0, stream>>>(Wfc, Wh, Wl);
    x_to_bf<<<6400, 256, 0, stream>>>(x, xall);
    prep_xl4<<<2048, 256, 0, stream>>>(x, xl4);
    prep_rec<<<dim3(32, 32), 256, 0, stream>>>(rec, msk, bin, Bc, partc);
    colsum2<<<8, 256, 0, stream>>>(partc, cs);
    ffpre_gemm<<<dim3(16, 8), 512, 0, stream>>>(xall, xl4, Wh, Wl, ffpre);
    ff_hi_gemm<<<3200, 512, 0, stream>>>(xall, Wh, cs, AF, out);
    lif0<<<256, 512, 0, stream>>>(ffpre, spk, memb, out, flags);
    for (int t = 1; t <= NPRE; ++t){
        gemm_pre<<<256, 512, 0, stream>>>(Bc, spk, flags, part, t);
        lif_pre<<<256, 512, 0, stream>>>(ffpre, cs, part, AF, spk, memb, out, flags, t);
    }
    snn_tail<<<256, 512, 0, stream>>>(Bc, x, Wfc, cs, AF, flags, spk, memb, part, sync, out);
}